// Round 4
// baseline (481.613 us; speedup 1.0000x reference)
//
#include <hip/hip_runtime.h>
#include <hip/hip_bf16.h>
#include <cstdint>
#include <cstddef>

typedef unsigned short u16;
typedef __attribute__((ext_vector_type(8))) short bf16x8;
typedef __attribute__((ext_vector_type(4))) float f32x4;

#define MFMA16(a,b,c) __builtin_amdgcn_mfma_f32_16x16x32_bf16(a,b,c,0,0,0)
#define GLL16(gp, lp) __builtin_amdgcn_global_load_lds( \
    (const __attribute__((address_space(1))) void*)(gp), \
    (__attribute__((address_space(3))) void*)(lp), 16, 0, 0)

static constexpr int kB = 8, kH = 12, kN = 1025, kC = 768, kD = 64;
static constexpr int kBH = kB*kH;          // 96
static constexpr int kNP = 1056;           // padded N (33*32)
static constexpr int kM  = kB*kN;          // 8200
static constexpr float kScale = 0.125f;

__device__ __forceinline__ u16 f2b(float f){
  unsigned u = __builtin_bit_cast(unsigned, f);
  u = (u + 0x7fffu + ((u>>16)&1u)) >> 16;
  return (u16)u;
}
__device__ __forceinline__ float b2f(u16 s){
  unsigned u = ((unsigned)s)<<16;
  return __builtin_bit_cast(float, u);
}

// ---------------- conversions ----------------
__global__ void k_conv_x(const float4* __restrict__ x, u16* __restrict__ out, int n4){
  int i = blockIdx.x*blockDim.x + threadIdx.x;
  int stride = gridDim.x*blockDim.x;
  for (; i<n4; i+=stride){
    float4 v = x[i];
    ushort4 o;
    o.x=f2b(v.x); o.y=f2b(v.y); o.z=f2b(v.z); o.w=f2b(v.w);
    *reinterpret_cast<ushort4*>(out + (size_t)i*4) = o;
  }
}

__global__ void k_conv_w(const float* __restrict__ w0, const float* __restrict__ w1,
                         const float* __restrict__ w2, const float* __restrict__ w3,
                         u16* __restrict__ out){
  const float* ws[4] = {w0,w1,w2,w3};
  int sel = blockIdx.y;
  const float4* src = reinterpret_cast<const float4*>(ws[sel]);
  int i = blockIdx.x*blockDim.x + threadIdx.x;   // 0..147455
  float4 v = src[i];
  ushort4 o;
  o.x=f2b(v.x); o.y=f2b(v.y); o.z=f2b(v.z); o.w=f2b(v.w);
  *reinterpret_cast<ushort4*>(out + (size_t)sel*589824 + (size_t)i*4) = o;
}

// mask may arrive as bool8 / int32 / float32 — detect via nonzero-byte density.
__global__ void k_mask(const unsigned char* __restrict__ m, int* __restrict__ out, int n){
  __shared__ int cnt;
  if (threadIdx.x==0) cnt = 0;
  __syncthreads();
  int local = 0;
  for (int i=threadIdx.x; i<1024; i+=blockDim.x) local += (m[i]!=0);
  atomicAdd(&cnt, local);
  __syncthreads();
  bool b8 = (cnt > 512);
  for (int i=threadIdx.x; i<n; i+=blockDim.x){
    int v = b8 ? (m[i]!=0) : (reinterpret_cast<const int*>(m)[i] != 0);
    out[i] = v;
  }
}

// ---------------- 128x128 GEMM (m97 structure + LDS-transpose epilogue) ------
// MODE 0: qkv -> bf16 matrix [kM][2304] via LDS transpose + dwordx4 stores
// MODE 1: proj -> f32 out [kM][768] + bias (scalar dword stores)
template<int MODE>
__global__ __launch_bounds__(256) void k_gemm128(const u16* __restrict__ A,
      const u16* __restrict__ wb, const float* __restrict__ bias,
      u16* __restrict__ outb, float* __restrict__ outf){
  __shared__ union SM {
    struct { u16 a[128*32]; u16 b[128*32]; } s;   // 16 KB staging
    u16 c[128*136];                                // 34 KB epilogue tile
  } sm;
  const int m0 = blockIdx.x*128;
  const int N0 = blockIdx.y*128;
  const int sel = (MODE==0) ? (N0/768) : 3;
  const int jb  = (MODE==0) ? (N0%768) : N0;
  const u16* W = wb + (size_t)sel*589824;
  const int t = threadIdx.x;
  const int wave = t>>6, lane = t&63;
  const int g = lane>>4, cl = lane&15;
  const int wr2 = (wave>>1)*64, wc2 = (wave&1)*64;

  const int cid0 = wave*64 + lane;
  const int cid1 = cid0 + 256;
  const int ar0 = m0 + (cid0>>2) < kM ? m0 + (cid0>>2) : kM-1;
  const int ar1 = m0 + (cid1>>2) < kM ? m0 + (cid1>>2) : kM-1;
  const int ac0 = (cid0&3)<<3, ac1 = (cid1&3)<<3;
  const int br0 = jb + (cid0>>2), br1 = jb + (cid1>>2);
  u16* lA0 = &sm.s.a[(wave*64)*8];
  u16* lA1 = &sm.s.a[(256 + wave*64)*8];
  u16* lB0 = &sm.s.b[(wave*64)*8];
  u16* lB1 = &sm.s.b[(256 + wave*64)*8];

  f32x4 acc[4][4];
  #pragma unroll
  for (int i=0;i<4;i++)
    #pragma unroll
    for (int j=0;j<4;j++) acc[i][j] = (f32x4){0.f,0.f,0.f,0.f};

  for (int k0=0; k0<768; k0+=32){
    __syncthreads();
    GLL16(A + (size_t)ar0*768 + k0 + ac0, lA0);
    GLL16(A + (size_t)ar1*768 + k0 + ac1, lA1);
    GLL16(W + (size_t)br0*768 + k0 + ac0, lB0);
    GLL16(W + (size_t)br1*768 + k0 + ac1, lB1);
    __syncthreads();
    bf16x8 af[4], bfg[4];
    #pragma unroll
    for (int fm=0; fm<4; fm++)
      af[fm] = *reinterpret_cast<const bf16x8*>(&sm.s.a[(wr2+fm*16+cl)*32 + g*8]);
    #pragma unroll
    for (int fn=0; fn<4; fn++)
      bfg[fn] = *reinterpret_cast<const bf16x8*>(&sm.s.b[(wc2+fn*16+cl)*32 + g*8]);
    #pragma unroll
    for (int fm=0; fm<4; fm++)
      #pragma unroll
      for (int fn=0; fn<4; fn++)
        acc[fm][fn] = MFMA16(af[fm], bfg[fn], acc[fm][fn]);
  }

  if (MODE==0){
    __syncthreads();    // staging reads done; safe to overwrite as C-tile
    #pragma unroll
    for (int fm=0; fm<4; fm++)
      #pragma unroll
      for (int fn=0; fn<4; fn++)
        #pragma unroll
        for (int i=0;i<4;i++){
          int r = wr2 + fm*16 + g*4 + i;
          int c = wc2 + fn*16 + cl;
          sm.c[r*136 + c] = f2b(acc[fm][fn][i]);
        }
    __syncthreads();
    // 2048 chunks of 8 u16; 256 B contiguous per 16 lanes
    #pragma unroll
    for (int it=0; it<8; it++){
      int cid = t + it*256;
      int r = cid >> 4, cc = (cid & 15) * 8;
      int gm = m0 + r;
      if (gm < kM){
        *reinterpret_cast<uint4*>(&outb[(size_t)gm*2304 + N0 + cc]) =
            *reinterpret_cast<const uint4*>(&sm.c[r*136 + cc]);
      }
    }
  } else {
    #pragma unroll
    for (int fm=0; fm<4; fm++)
      #pragma unroll
      for (int fn=0; fn<4; fn++)
        #pragma unroll
        for (int i=0;i<4;i++){
          int gm = m0 + wr2 + fm*16 + g*4 + i;
          if (gm >= kM) continue;
          int gc = jb + wc2 + fn*16 + cl;
          outf[(size_t)gm*768 + gc] = acc[fm][fn][i] + bias[gc];
        }
  }
}

// ---------------- depthwise pool + layernorm (reads [kM][2304] qkv matrix) ---
__global__ __launch_bounds__(256) void k_pool3(const u16* __restrict__ qkvmat,
    const float* __restrict__ wq, const float* __restrict__ wk, const float* __restrict__ wv,
    const float* __restrict__ gq, const float* __restrict__ bq,
    const float* __restrict__ gk, const float* __restrict__ bk,
    const float* __restrict__ gv, const float* __restrict__ bv,
    u16* __restrict__ Qp, u16* __restrict__ Kp, u16* __restrict__ Vt){
  const int which = blockIdx.y;
  const float* w9 = (which==0)?wq:(which==1)?wk:wv;
  const float* gg = (which==0)?gq:(which==1)?gk:gv;
  const float* bb2= (which==0)?bq:(which==1)?bk:bv;
  const int transposed = (which==2);
  u16* out = (which==0)?Qp:(which==1)?Kp:Vt;

  const int wave = threadIdx.x>>6, d = threadIdx.x&63;
  const int grp = blockIdx.x % 264;
  const int bh  = blockIdx.x / 264;
  const int b = bh/12, h = bh - b*12;
  const int np  = grp*4 + wave;
  float v = 0.f;
  if (np < kN){
    const u16* base = qkvmat + ((size_t)b*1025)*2304 + which*768 + h*64;
    if (np == 0){
      v = b2f(base[d]);
    } else {
      int y = (np-1)>>5, x = (np-1)&31;
      #pragma unroll
      for (int ky=0; ky<3; ky++){
        int yy = y+ky-1;
        if (yy<0 || yy>31) continue;
        #pragma unroll
        for (int kx=0; kx<3; kx++){
          int xx = x+kx-1;
          if (xx<0 || xx>31) continue;
          v += w9[d*9+ky*3+kx] * b2f(base[(size_t)(1+yy*32+xx)*2304 + d]);
        }
      }
    }
    float s = v, s2 = v*v;
    #pragma unroll
    for (int off=1; off<64; off<<=1){ s += __shfl_xor(s, off); s2 += __shfl_xor(s2, off); }
    float mean = s*(1.f/64.f);
    float var  = s2*(1.f/64.f) - mean*mean;
    v = (v-mean)*rsqrtf(var+1e-5f)*gg[d] + bb2[d];
  }
  if (transposed) out[((size_t)bh*kD + d)*kNP + np] = f2b(v);
  else            out[((size_t)bh*kNP + np)*kD + d] = f2b(v);
}

// ---------------- attention: single QK^T pass + LDS e-tile ----------------
// |logit| <= 8 (LN'd q,k): no max pass. masked rows -> uniform 1/1025.
__global__ __launch_bounds__(256) void k_attn(const u16* __restrict__ Qp, const u16* __restrict__ Kp,
    const u16* __restrict__ Vt, const int* __restrict__ maskn,
    float* __restrict__ attn_out, u16* __restrict__ ctx){
  constexpr int LDE = 1064;
  __shared__ u16 E[16*LDE];
  __shared__ float Lrow[16];
  __shared__ float Linv[16];
  const int wave = threadIdx.x>>6, lane = threadIdx.x&63;
  const int bh = blockIdx.x / 65;
  const int qt = blockIdx.x % 65;
  const int b  = bh / 12, h = bh - b*12;
  const int qbase = qt*16;
  const int g = lane>>4, cl = lane&15;

  if (threadIdx.x < 16) Lrow[threadIdx.x] = 0.f;
  __syncthreads();

  const u16* qrow = Qp + ((size_t)bh*kNP + (qbase + cl))*kD + g*8;
  bf16x8 aq0 = *reinterpret_cast<const bf16x8*>(qrow);
  bf16x8 aq1 = *reinterpret_cast<const bf16x8*>(qrow + 32);

  float mq[4];
  #pragma unroll
  for (int i=0;i<4;i++){
    int qi = qbase + g*4 + i;
    mq[i] = (qi<kN && maskn[b*kN+qi]!=0) ? kScale : 0.f;
  }

  // ---- phase 1: QK^T -> e -> LDS, row sums ----
  const u16* kb = Kp + (size_t)bh*kNP*kD;
  float rsum[4] = {0.f,0.f,0.f,0.f};
  for (int kt=wave; kt<33; kt+=4){
    const int ktb = kt*32;
    const u16* kr = kb + (size_t)(ktb+cl)*kD + g*8;
    bf16x8 b00 = *reinterpret_cast<const bf16x8*>(kr);
    bf16x8 b01 = *reinterpret_cast<const bf16x8*>(kr+32);
    bf16x8 b10 = *reinterpret_cast<const bf16x8*>(kr+1024);
    bf16x8 b11 = *reinterpret_cast<const bf16x8*>(kr+1024+32);
    f32x4 s0 = {0.f,0.f,0.f,0.f}, s1 = {0.f,0.f,0.f,0.f};
    s0 = MFMA16(aq0,b00,s0); s0 = MFMA16(aq1,b01,s0);
    s1 = MFMA16(aq0,b10,s1); s1 = MFMA16(aq1,b11,s1);
    const bool v0 = (ktb+cl)<kN, v1 = (ktb+16+cl)<kN;
    #pragma unroll
    for (int i=0;i<4;i++){
      int row = g*4+i;
      float e0 = v0 ? __expf(s0[i]*mq[i]) : 0.f;
      float e1 = v1 ? __expf(s1[i]*mq[i]) : 0.f;
      rsum[i] += e0 + e1;
      E[row*LDE + ktb + cl]      = f2b(e0);
      E[row*LDE + ktb + 16 + cl] = f2b(e1);
    }
  }
  #pragma unroll
  for (int off=1; off<16; off<<=1){
    #pragma unroll
    for (int i=0;i<4;i++) rsum[i] += __shfl_xor(rsum[i], off);
  }
  if (cl == 0){
    #pragma unroll
    for (int i=0;i<4;i++) atomicAdd(&Lrow[g*4+i], rsum[i]);
  }
  __syncthreads();
  if (threadIdx.x < 16) Linv[threadIdx.x] = 1.f/Lrow[threadIdx.x];
  __syncthreads();

  // ---- phase 2a: attn tile as ONE contiguous span (full line coverage) ----
  // rows of this tile are adjacent in memory: 16*1025 floats.
  {
    size_t S = (size_t)bh*kN*kN + (size_t)qbase*kN;   // f32 elem offset
    float* tp = attn_out + S;
    int rows = kN - qbase; if (rows > 16) rows = 16;
    int T = rows*kN;
    int head = (int)((4 - (S & 3)) & 3);
    int body4 = (T - head) >> 2;
    int tail = T - head - body4*4;
    int t = threadIdx.x;
    if (t < head){
      int e = t;
      unsigned row = ((unsigned)(e*16369))>>24;
      int col = e - (int)row*kN;
      tp[e] = b2f(E[row*LDE+col]) * Linv[row];
    }
    if (t < tail){
      int e = head + body4*4 + t;
      unsigned row = ((unsigned)(e*16369))>>24;
      int col = e - (int)row*kN;
      tp[e] = b2f(E[row*LDE+col]) * Linv[row];
    }
    for (int idx = t; idx < body4; idx += 256){
      int e = head + idx*4;
      unsigned row0 = ((unsigned)(e*16369))>>24;
      unsigned row3 = ((unsigned)((e+3)*16369))>>24;
      float4 vv;
      if (row0 == row3){
        int col = e - (int)row0*kN;
        const u16* ep = &E[row0*LDE + col];
        float li = Linv[row0];
        vv.x = b2f(ep[0])*li; vv.y = b2f(ep[1])*li;
        vv.z = b2f(ep[2])*li; vv.w = b2f(ep[3])*li;
      } else {
        float tmp[4];
        #pragma unroll
        for (int j=0;j<4;j++){
          int ee = e+j;
          unsigned row = ((unsigned)(ee*16369))>>24;
          int col = ee - (int)row*kN;
          tmp[j] = b2f(E[row*LDE+col]) * Linv[row];
        }
        vv.x=tmp[0]; vv.y=tmp[1]; vv.z=tmp[2]; vv.w=tmp[3];
      }
      *reinterpret_cast<float4*>(tp + e) = vv;
    }
  }

  // ---- phase 2b: PV from LDS e-tile; wave owns 16 d-cols ----
  const int d0 = wave*16;
  f32x4 oacc = (f32x4){0.f,0.f,0.f,0.f};
  const u16* vb = Vt + ((size_t)bh*kD + d0 + cl)*kNP;
  for (int kt=0; kt<33; kt++){
    const int ko = kt*32 + g*8;
    bf16x8 pa  = *reinterpret_cast<const bf16x8*>(&E[cl*LDE + ko]);
    bf16x8 vbf = *reinterpret_cast<const bf16x8*>(vb + ko);
    oacc = MFMA16(pa, vbf, oacc);
  }
  #pragma unroll
  for (int i=0;i<4;i++){
    int row = g*4+i, qi = qbase+row;
    if (qi < kN){
      float val = oacc[i] * Linv[row];
      int dd = d0 + cl;
      if (qi >= 1) val += b2f(Qp[((size_t)bh*kNP + qi)*kD + dd]);
      ctx[((size_t)(b*kN + qi))*kC + h*kD + dd] = f2b(val);
    }
  }
}

extern "C" void kernel_launch(void* const* d_in, const int* in_sizes, int n_in,
                              void* d_out, int out_size, void* d_ws, size_t ws_size,
                              hipStream_t stream) {
  const float* x    = (const float*)d_in[0];
  const void*  msk  = d_in[1];
  const float* Wq   = (const float*)d_in[2];
  const float* Wk   = (const float*)d_in[3];
  const float* Wv   = (const float*)d_in[4];
  const float* pw_q = (const float*)d_in[5];
  const float* pw_k = (const float*)d_in[6];
  const float* pw_v = (const float*)d_in[7];
  const float* gq   = (const float*)d_in[8];
  const float* bq   = (const float*)d_in[9];
  const float* gk   = (const float*)d_in[10];
  const float* bk   = (const float*)d_in[11];
  const float* gv   = (const float*)d_in[12];
  const float* bv   = (const float*)d_in[13];
  const float* Wp   = (const float*)d_in[14];
  const float* bp   = (const float*)d_in[15];

  char* ws = (char*)d_ws;
  u16* xb     = (u16*)(ws + 0);            // 12,595,200 B
  u16* wb     = (u16*)(ws + 12595200);     // 4,718,592 B (Wq,Wk,Wv,Wp)
  int* maskn  = (int*)(ws + 17313792);
  u16* qkvmat = (u16*)(ws + 17346816);     // [8200][2304] bf16 = 37,785,600 B
  u16* Qp     = (u16*)(ws + 55132416);
  u16* Kp     = (u16*)(ws + 68108544);
  u16* Vt     = (u16*)(ws + 81084672);
  u16* ctx    = (u16*)(ws + 17346816);     // aliases qkvmat (free after pooling)

  float* out1 = (float*)d_out;
  float* attn = out1 + (size_t)kM*kC;

  k_conv_x<<<2048, 256, 0, stream>>>(reinterpret_cast<const float4*>(x), xb, (kM*kC)/4);
  k_conv_w<<<dim3(576,4), 256, 0, stream>>>(Wq, Wk, Wv, Wp, wb);
  k_mask<<<1, 256, 0, stream>>>((const unsigned char*)msk, maskn, kM);
  k_gemm128<0><<<dim3(65,18), 256, 0, stream>>>(xb, wb, nullptr, qkvmat, nullptr);
  k_pool3<<<dim3(kBH*264,3), 256, 0, stream>>>(qkvmat, pw_q, pw_k, pw_v,
                                               gq, bq, gk, bk, gv, bv, Qp, Kp, Vt);
  k_attn<<<96*65, 256, 0, stream>>>(Qp, Kp, Vt, maskn, attn, ctx);
  k_gemm128<1><<<dim3(65,6), 256, 0, stream>>>(ctx, wb, bp, nullptr, out1);
}

// Round 5
// 434.503 us; speedup vs baseline: 1.1084x; 1.1084x over previous
//
#include <hip/hip_runtime.h>
#include <hip/hip_bf16.h>
#include <cstdint>
#include <cstddef>

typedef unsigned short u16;
typedef __attribute__((ext_vector_type(8))) short bf16x8;
typedef __attribute__((ext_vector_type(4))) float f32x4;

#define MFMA16(a,b,c) __builtin_amdgcn_mfma_f32_16x16x32_bf16(a,b,c,0,0,0)
#define GLL16(gp, lp) __builtin_amdgcn_global_load_lds( \
    (const __attribute__((address_space(1))) void*)(gp), \
    (__attribute__((address_space(3))) void*)(lp), 16, 0, 0)

static constexpr int kB = 8, kH = 12, kN = 1025, kC = 768, kD = 64;
static constexpr int kBH = kB*kH;          // 96
static constexpr int kNP = 1056;           // padded N (33*32)
static constexpr int kM  = kB*kN;          // 8200
static constexpr float kScale = 0.125f;

__device__ __forceinline__ u16 f2b(float f){
  unsigned u = __builtin_bit_cast(unsigned, f);
  u = (u + 0x7fffu + ((u>>16)&1u)) >> 16;
  return (u16)u;
}
__device__ __forceinline__ float b2f(u16 s){
  unsigned u = ((unsigned)s)<<16;
  return __builtin_bit_cast(float, u);
}

// ---------------- fused prep: x->bf16, weights->bf16, mask normalize --------
// blocks [0,6150): conv_x ; [6150,8454): conv_w ; [8454,8486): mask
__global__ __launch_bounds__(256) void k_prep(const float4* __restrict__ x,
    const float* __restrict__ w0, const float* __restrict__ w1,
    const float* __restrict__ w2, const float* __restrict__ w3,
    const unsigned char* __restrict__ m,
    u16* __restrict__ xb, u16* __restrict__ wb, int* __restrict__ maskn){
  __shared__ int cnt;
  const int bid = blockIdx.x;
  if (bid < 6150){
    int i = bid*256 + threadIdx.x;          // exactly 1,574,400
    float4 v = x[i];
    ushort4 o; o.x=f2b(v.x); o.y=f2b(v.y); o.z=f2b(v.z); o.w=f2b(v.w);
    *reinterpret_cast<ushort4*>(xb + (size_t)i*4) = o;
  } else if (bid < 8454){
    int j = (bid-6150)*256 + threadIdx.x;   // exactly 589,824
    int sel = j/147456, i = j - sel*147456;
    const float* ws[4] = {w0,w1,w2,w3};
    float4 v = reinterpret_cast<const float4*>(ws[sel])[i];
    ushort4 o; o.x=f2b(v.x); o.y=f2b(v.y); o.z=f2b(v.z); o.w=f2b(v.w);
    *reinterpret_cast<ushort4*>(wb + (size_t)sel*589824 + (size_t)i*4) = o;
  } else {
    // mask dtype detect (bool8 vs int32/f32) on first 1024 bytes, then slice
    if (threadIdx.x==0) cnt = 0;
    __syncthreads();
    int local = 0;
    for (int i=threadIdx.x; i<1024; i+=256) local += (m[i]!=0);
    atomicAdd(&cnt, local);
    __syncthreads();
    bool b8 = (cnt > 512);
    int lb = bid - 8454;                    // 0..31
    for (int i = lb*256 + threadIdx.x; i < kM; i += 32*256){
      int v = b8 ? (m[i]!=0) : (reinterpret_cast<const int*>(m)[i] != 0);
      maskn[i] = v;
    }
  }
}

// ---------------- 128x128 GEMM (m97 structure + LDS-transpose epilogue) ------
// MODE 0: qkv -> bf16 matrix [kM][2304] via LDS transpose + dwordx4 stores
// MODE 1: proj -> f32 out [kM][768] + bias
template<int MODE>
__global__ __launch_bounds__(256) void k_gemm128(const u16* __restrict__ A,
      const u16* __restrict__ wb, const float* __restrict__ bias,
      u16* __restrict__ outb, float* __restrict__ outf){
  __shared__ union SM {
    struct { u16 a[128*32]; u16 b[128*32]; } s;   // 16 KB staging
    u16 c[128*136];                                // 34 KB epilogue tile
  } sm;
  const int m0 = blockIdx.x*128;
  const int N0 = blockIdx.y*128;
  const int sel = (MODE==0) ? (N0/768) : 3;
  const int jb  = (MODE==0) ? (N0%768) : N0;
  const u16* W = wb + (size_t)sel*589824;
  const int t = threadIdx.x;
  const int wave = t>>6, lane = t&63;
  const int g = lane>>4, cl = lane&15;
  const int wr2 = (wave>>1)*64, wc2 = (wave&1)*64;

  const int cid0 = wave*64 + lane;
  const int cid1 = cid0 + 256;
  const int ar0 = m0 + (cid0>>2) < kM ? m0 + (cid0>>2) : kM-1;
  const int ar1 = m0 + (cid1>>2) < kM ? m0 + (cid1>>2) : kM-1;
  const int ac0 = (cid0&3)<<3, ac1 = (cid1&3)<<3;
  const int br0 = jb + (cid0>>2), br1 = jb + (cid1>>2);
  u16* lA0 = &sm.s.a[(wave*64)*8];
  u16* lA1 = &sm.s.a[(256 + wave*64)*8];
  u16* lB0 = &sm.s.b[(wave*64)*8];
  u16* lB1 = &sm.s.b[(256 + wave*64)*8];

  f32x4 acc[4][4];
  #pragma unroll
  for (int i=0;i<4;i++)
    #pragma unroll
    for (int j=0;j<4;j++) acc[i][j] = (f32x4){0.f,0.f,0.f,0.f};

  for (int k0=0; k0<768; k0+=32){
    __syncthreads();
    GLL16(A + (size_t)ar0*768 + k0 + ac0, lA0);
    GLL16(A + (size_t)ar1*768 + k0 + ac1, lA1);
    GLL16(W + (size_t)br0*768 + k0 + ac0, lB0);
    GLL16(W + (size_t)br1*768 + k0 + ac1, lB1);
    __syncthreads();
    bf16x8 af[4], bfg[4];
    #pragma unroll
    for (int fm=0; fm<4; fm++)
      af[fm] = *reinterpret_cast<const bf16x8*>(&sm.s.a[(wr2+fm*16+cl)*32 + g*8]);
    #pragma unroll
    for (int fn=0; fn<4; fn++)
      bfg[fn] = *reinterpret_cast<const bf16x8*>(&sm.s.b[(wc2+fn*16+cl)*32 + g*8]);
    #pragma unroll
    for (int fm=0; fm<4; fm++)
      #pragma unroll
      for (int fn=0; fn<4; fn++)
        acc[fm][fn] = MFMA16(af[fm], bfg[fn], acc[fm][fn]);
  }

  if (MODE==0){
    __syncthreads();
    #pragma unroll
    for (int fm=0; fm<4; fm++)
      #pragma unroll
      for (int fn=0; fn<4; fn++)
        #pragma unroll
        for (int i=0;i<4;i++){
          int r = wr2 + fm*16 + g*4 + i;
          int c = wc2 + fn*16 + cl;
          sm.c[r*136 + c] = f2b(acc[fm][fn][i]);
        }
    __syncthreads();
    #pragma unroll
    for (int it=0; it<8; it++){
      int cid = t + it*256;
      int r = cid >> 4, cc = (cid & 15) * 8;
      int gm = m0 + r;
      if (gm < kM){
        *reinterpret_cast<uint4*>(&outb[(size_t)gm*2304 + N0 + cc]) =
            *reinterpret_cast<const uint4*>(&sm.c[r*136 + cc]);
      }
    }
  } else {
    #pragma unroll
    for (int fm=0; fm<4; fm++)
      #pragma unroll
      for (int fn=0; fn<4; fn++)
        #pragma unroll
        for (int i=0;i<4;i++){
          int gm = m0 + wr2 + fm*16 + g*4 + i;
          if (gm >= kM) continue;
          int gc = jb + wc2 + fn*16 + cl;
          outf[(size_t)gm*768 + gc] = acc[fm][fn][i] + bias[gc];
        }
  }
}

// ---------------- depthwise pool + LN; block = (bh, 64-np slab, which) -------
// V (which==2) goes through an LDS transpose so the [d][np] store is coalesced.
__global__ __launch_bounds__(256) void k_pool3(const u16* __restrict__ qkvmat,
    const float* __restrict__ wq, const float* __restrict__ wk, const float* __restrict__ wv,
    const float* __restrict__ gq, const float* __restrict__ bq,
    const float* __restrict__ gk, const float* __restrict__ bk,
    const float* __restrict__ gv, const float* __restrict__ bv,
    u16* __restrict__ Qp, u16* __restrict__ Kp, u16* __restrict__ Vt){
  __shared__ u16 vt[64][72];                 // 9216 B, 16B-aligned rows
  const int which = blockIdx.y;
  const float* w9 = (which==0)?wq:(which==1)?wk:wv;
  const float* gg = (which==0)?gq:(which==1)?gk:gv;
  const float* bb2= (which==0)?bq:(which==1)?bk:bv;
  u16* out = (which==0)?Qp:(which==1)?Kp:Vt;

  const int wave = threadIdx.x>>6, d = threadIdx.x&63;
  const int nb  = blockIdx.x % 17;           // 64-np slab
  const int bh  = blockIdx.x / 17;
  const int b = bh/12, h = bh - b*12;
  const int np0 = nb*64;
  const u16* base = qkvmat + ((size_t)b*1025)*2304 + which*768 + h*64;

  float wreg[9];
  #pragma unroll
  for (int j=0;j<9;j++) wreg[j] = w9[d*9+j];
  const float gd = gg[d], bd = bb2[d];

  for (int iter=0; iter<16; ++iter){
    const int np = np0 + iter*4 + wave;
    float v = 0.f;
    if (np < kN){
      if (np == 0){
        v = b2f(base[d]);
      } else {
        int y = (np-1)>>5, x = (np-1)&31;
        #pragma unroll
        for (int ky=0; ky<3; ky++){
          int yy = y+ky-1;
          if (yy<0 || yy>31) continue;
          #pragma unroll
          for (int kx=0; kx<3; kx++){
            int xx = x+kx-1;
            if (xx<0 || xx>31) continue;
            v += wreg[ky*3+kx] * b2f(base[(size_t)(1+yy*32+xx)*2304 + d]);
          }
        }
      }
      float s = v, s2 = v*v;
      #pragma unroll
      for (int off=1; off<64; off<<=1){ s += __shfl_xor(s, off); s2 += __shfl_xor(s2, off); }
      float mean = s*(1.f/64.f);
      float var  = s2*(1.f/64.f) - mean*mean;
      v = (v-mean)*rsqrtf(var+1e-5f)*gd + bd;
    }
    if (which==2) vt[d][iter*4+wave] = f2b(v);
    else if (np < kNP) out[((size_t)bh*kNP + np)*kD + d] = f2b(v);
  }

  if (which==2){
    __syncthreads();
    const int dr = threadIdx.x>>2, seg = threadIdx.x&3;
    if (np0 + seg*16 < kNP){
      u16* dst = Vt + ((size_t)bh*kD + dr)*kNP + np0 + seg*16;
      *reinterpret_cast<uint4*>(dst)     = *reinterpret_cast<const uint4*>(&vt[dr][seg*16]);
      *reinterpret_cast<uint4*>(dst + 8) = *reinterpret_cast<const uint4*>(&vt[dr][seg*16+8]);
    }
  }
}

// ---------------- attention: single QK^T pass + LDS e-tile ----------------
// |logit| <= 8 (LN'd q,k): no max pass. masked rows -> uniform 1/1025.
// XCD-swizzled: all 65 q-tiles of one bh land on one XCD (K/V L2-resident).
__global__ __launch_bounds__(256) void k_attn(const u16* __restrict__ Qp, const u16* __restrict__ Kp,
    const u16* __restrict__ Vt, const int* __restrict__ maskn,
    float* __restrict__ attn_out, u16* __restrict__ ctx){
  constexpr int LDE = 1064;
  __shared__ u16 E[16*LDE];
  __shared__ float Lrow[16];
  __shared__ float Linv[16];
  const int wave = threadIdx.x>>6, lane = threadIdx.x&63;
  const int xcd  = blockIdx.x & 7;           // dispatch round-robins XCDs
  const int slot = blockIdx.x >> 3;          // 0..779
  const int bh = xcd*12 + slot/65;
  const int qt = slot%65;
  const int b  = bh / 12, h = bh - b*12;
  const int qbase = qt*16;
  const int g = lane>>4, cl = lane&15;

  if (threadIdx.x < 16) Lrow[threadIdx.x] = 0.f;
  __syncthreads();

  const u16* qrow = Qp + ((size_t)bh*kNP + (qbase + cl))*kD + g*8;
  bf16x8 aq0 = *reinterpret_cast<const bf16x8*>(qrow);
  bf16x8 aq1 = *reinterpret_cast<const bf16x8*>(qrow + 32);

  float mq[4];
  #pragma unroll
  for (int i=0;i<4;i++){
    int qi = qbase + g*4 + i;
    mq[i] = (qi<kN && maskn[b*kN+qi]!=0) ? kScale : 0.f;
  }

  // ---- phase 1: QK^T -> e -> LDS, row sums ----
  const u16* kb = Kp + (size_t)bh*kNP*kD;
  float rsum[4] = {0.f,0.f,0.f,0.f};
  #pragma unroll 2
  for (int kt=wave; kt<33; kt+=4){
    const int ktb = kt*32;
    const u16* kr = kb + (size_t)(ktb+cl)*kD + g*8;
    bf16x8 b00 = *reinterpret_cast<const bf16x8*>(kr);
    bf16x8 b01 = *reinterpret_cast<const bf16x8*>(kr+32);
    bf16x8 b10 = *reinterpret_cast<const bf16x8*>(kr+1024);
    bf16x8 b11 = *reinterpret_cast<const bf16x8*>(kr+1024+32);
    f32x4 s0 = {0.f,0.f,0.f,0.f}, s1 = {0.f,0.f,0.f,0.f};
    s0 = MFMA16(aq0,b00,s0); s0 = MFMA16(aq1,b01,s0);
    s1 = MFMA16(aq0,b10,s1); s1 = MFMA16(aq1,b11,s1);
    const bool v0 = (ktb+cl)<kN, v1 = (ktb+16+cl)<kN;
    #pragma unroll
    for (int i=0;i<4;i++){
      int row = g*4+i;
      float e0 = v0 ? __expf(s0[i]*mq[i]) : 0.f;
      float e1 = v1 ? __expf(s1[i]*mq[i]) : 0.f;
      rsum[i] += e0 + e1;
      E[row*LDE + ktb + cl]      = f2b(e0);
      E[row*LDE + ktb + 16 + cl] = f2b(e1);
    }
  }
  #pragma unroll
  for (int off=1; off<16; off<<=1){
    #pragma unroll
    for (int i=0;i<4;i++) rsum[i] += __shfl_xor(rsum[i], off);
  }
  if (cl == 0){
    #pragma unroll
    for (int i=0;i<4;i++) atomicAdd(&Lrow[g*4+i], rsum[i]);
  }
  __syncthreads();
  if (threadIdx.x < 16) Linv[threadIdx.x] = 1.f/Lrow[threadIdx.x];
  __syncthreads();

  // ---- phase 2a: attn tile as ONE contiguous span ----
  {
    size_t S = (size_t)bh*kN*kN + (size_t)qbase*kN;
    float* tp = attn_out + S;
    int rows = kN - qbase; if (rows > 16) rows = 16;
    int T = rows*kN;
    int head = (int)((4 - (S & 3)) & 3);
    int body4 = (T - head) >> 2;
    int tail = T - head - body4*4;
    int t = threadIdx.x;
    if (t < head){
      int e = t;
      unsigned row = ((unsigned)(e*16369))>>24;
      int col = e - (int)row*kN;
      tp[e] = b2f(E[row*LDE+col]) * Linv[row];
    }
    if (t < tail){
      int e = head + body4*4 + t;
      unsigned row = ((unsigned)(e*16369))>>24;
      int col = e - (int)row*kN;
      tp[e] = b2f(E[row*LDE+col]) * Linv[row];
    }
    for (int idx = t; idx < body4; idx += 256){
      int e = head + idx*4;
      unsigned row0 = ((unsigned)(e*16369))>>24;
      unsigned row3 = ((unsigned)((e+3)*16369))>>24;
      float4 vv;
      if (row0 == row3){
        int col = e - (int)row0*kN;
        const u16* ep = &E[row0*LDE + col];
        float li = Linv[row0];
        vv.x = b2f(ep[0])*li; vv.y = b2f(ep[1])*li;
        vv.z = b2f(ep[2])*li; vv.w = b2f(ep[3])*li;
      } else {
        float tmp[4];
        #pragma unroll
        for (int j=0;j<4;j++){
          int ee = e+j;
          unsigned row = ((unsigned)(ee*16369))>>24;
          int col = ee - (int)row*kN;
          tmp[j] = b2f(E[row*LDE+col]) * Linv[row];
        }
        vv.x=tmp[0]; vv.y=tmp[1]; vv.z=tmp[2]; vv.w=tmp[3];
      }
      *reinterpret_cast<float4*>(tp + e) = vv;
    }
  }

  // ---- phase 2b: PV, 4-deep load pipeline; wave owns 16 d-cols ----
  const int d0 = wave*16;
  f32x4 oacc = (f32x4){0.f,0.f,0.f,0.f};
  const u16* vb = Vt + ((size_t)bh*kD + d0 + cl)*kNP;
  for (int kt0=0; kt0<32; kt0+=4){
    bf16x8 pa[4], vv[4];
    #pragma unroll
    for (int j=0;j<4;j++){
      const int ko = (kt0+j)*32 + g*8;
      pa[j] = *reinterpret_cast<const bf16x8*>(&E[cl*LDE + ko]);
      vv[j] = *reinterpret_cast<const bf16x8*>(vb + ko);
    }
    #pragma unroll
    for (int j=0;j<4;j++) oacc = MFMA16(pa[j], vv[j], oacc);
  }
  {
    const int ko = 32*32 + g*8;
    bf16x8 pa = *reinterpret_cast<const bf16x8*>(&E[cl*LDE + ko]);
    bf16x8 vv = *reinterpret_cast<const bf16x8*>(vb + ko);
    oacc = MFMA16(pa, vv, oacc);
  }
  #pragma unroll
  for (int i=0;i<4;i++){
    int row = g*4+i, qi = qbase+row;
    if (qi < kN){
      float val = oacc[i] * Linv[row];
      int dd = d0 + cl;
      if (qi >= 1) val += b2f(Qp[((size_t)bh*kNP + qi)*kD + dd]);
      ctx[((size_t)(b*kN + qi))*kC + h*kD + dd] = f2b(val);
    }
  }
}

extern "C" void kernel_launch(void* const* d_in, const int* in_sizes, int n_in,
                              void* d_out, int out_size, void* d_ws, size_t ws_size,
                              hipStream_t stream) {
  const float* x    = (const float*)d_in[0];
  const void*  msk  = d_in[1];
  const float* Wq   = (const float*)d_in[2];
  const float* Wk   = (const float*)d_in[3];
  const float* Wv   = (const float*)d_in[4];
  const float* pw_q = (const float*)d_in[5];
  const float* pw_k = (const float*)d_in[6];
  const float* pw_v = (const float*)d_in[7];
  const float* gq   = (const float*)d_in[8];
  const float* bq   = (const float*)d_in[9];
  const float* gk   = (const float*)d_in[10];
  const float* bk   = (const float*)d_in[11];
  const float* gv   = (const float*)d_in[12];
  const float* bv   = (const float*)d_in[13];
  const float* Wp   = (const float*)d_in[14];
  const float* bp   = (const float*)d_in[15];

  char* ws = (char*)d_ws;
  u16* xb     = (u16*)(ws + 0);            // 12,595,200 B
  u16* wb     = (u16*)(ws + 12595200);     // 4,718,592 B (Wq,Wk,Wv,Wp)
  int* maskn  = (int*)(ws + 17313792);
  u16* qkvmat = (u16*)(ws + 17346816);     // [8200][2304] bf16 = 37,785,600 B
  u16* Qp     = (u16*)(ws + 55132416);
  u16* Kp     = (u16*)(ws + 68108544);
  u16* Vt     = (u16*)(ws + 81084672);
  u16* ctx    = (u16*)(ws + 17346816);     // aliases qkvmat (free after pooling)

  float* out1 = (float*)d_out;
  float* attn = out1 + (size_t)kM*kC;

  k_prep<<<8486, 256, 0, stream>>>(reinterpret_cast<const float4*>(x),
                                   Wq, Wk, Wv, Wp, (const unsigned char*)msk,
                                   xb, wb, maskn);
  k_gemm128<0><<<dim3(65,18), 256, 0, stream>>>(xb, wb, nullptr, qkvmat, nullptr);
  k_pool3<<<dim3(96*17,3), 256, 0, stream>>>(qkvmat, pw_q, pw_k, pw_v,
                                             gq, bq, gk, bk, gv, bv, Qp, Kp, Vt);
  k_attn<<<96*65, 256, 0, stream>>>(Qp, Kp, Vt, maskn, attn, ctx);
  k_gemm128<1><<<dim3(65,6), 256, 0, stream>>>(ctx, wb, bp, nullptr, out1);
}

// Round 6
// 412.278 us; speedup vs baseline: 1.1682x; 1.0539x over previous
//
#include <hip/hip_runtime.h>
#include <hip/hip_bf16.h>
#include <cstdint>
#include <cstddef>

typedef unsigned short u16;
typedef __attribute__((ext_vector_type(8))) short bf16x8;
typedef __attribute__((ext_vector_type(4))) float f32x4;

#define MFMA16(a,b,c) __builtin_amdgcn_mfma_f32_16x16x32_bf16(a,b,c,0,0,0)
#define GLL16(gp, lp) __builtin_amdgcn_global_load_lds( \
    (const __attribute__((address_space(1))) void*)(gp), \
    (__attribute__((address_space(3))) void*)(lp), 16, 0, 0)

static constexpr int kB = 8, kH = 12, kN = 1025, kC = 768, kD = 64;
static constexpr int kBH = kB*kH;          // 96
static constexpr int kNP = 1056;           // padded N (33*32)
static constexpr int kM  = kB*kN;          // 8200
static constexpr float kScale = 0.125f;

__device__ __forceinline__ u16 f2b(float f){
  unsigned u = __builtin_bit_cast(unsigned, f);
  u = (u + 0x7fffu + ((u>>16)&1u)) >> 16;
  return (u16)u;
}
__device__ __forceinline__ float b2f(u16 s){
  unsigned u = ((unsigned)s)<<16;
  return __builtin_bit_cast(float, u);
}
// bijective XCD-chunked swizzle (m204): contiguous work chunk per XCD
__device__ __forceinline__ int xcd_swz(int orig, int nwg){
  int q = nwg>>3, r = nwg&7;
  int xcd = orig&7, idx = orig>>3;
  return (xcd<r ? xcd*(q+1) : r*(q+1)+(xcd-r)*q) + idx;
}

// ---------------- fused prep: x->bf16, weights->bf16, mask normalize --------
// blocks [0,6150): conv_x ; [6150,8454): conv_w ; [8454,8486): mask
__global__ __launch_bounds__(256) void k_prep(const float4* __restrict__ x,
    const float* __restrict__ w0, const float* __restrict__ w1,
    const float* __restrict__ w2, const float* __restrict__ w3,
    const unsigned char* __restrict__ m,
    u16* __restrict__ xb, u16* __restrict__ wb, int* __restrict__ maskn){
  __shared__ int cnt;
  const int bid = blockIdx.x;
  if (bid < 6150){
    int i = bid*256 + threadIdx.x;          // exactly 1,574,400
    float4 v = x[i];
    ushort4 o; o.x=f2b(v.x); o.y=f2b(v.y); o.z=f2b(v.z); o.w=f2b(v.w);
    *reinterpret_cast<ushort4*>(xb + (size_t)i*4) = o;
  } else if (bid < 8454){
    int j = (bid-6150)*256 + threadIdx.x;   // exactly 589,824
    int sel = j/147456, i = j - sel*147456;
    const float* ws[4] = {w0,w1,w2,w3};
    float4 v = reinterpret_cast<const float4*>(ws[sel])[i];
    ushort4 o; o.x=f2b(v.x); o.y=f2b(v.y); o.z=f2b(v.z); o.w=f2b(v.w);
    *reinterpret_cast<ushort4*>(wb + (size_t)sel*589824 + (size_t)i*4) = o;
  } else {
    // mask dtype detect (bool8 vs int32/f32) on first 1024 bytes, then slice
    if (threadIdx.x==0) cnt = 0;
    __syncthreads();
    int local = 0;
    for (int i=threadIdx.x; i<1024; i+=256) local += (m[i]!=0);
    atomicAdd(&cnt, local);
    __syncthreads();
    bool b8 = (cnt > 512);
    int lb = bid - 8454;                    // 0..31
    for (int i = lb*256 + threadIdx.x; i < kM; i += 32*256){
      int v = b8 ? (m[i]!=0) : (reinterpret_cast<const int*>(m)[i] != 0);
      maskn[i] = v;
    }
  }
}

// ---------------- 128x128 GEMM (m97 structure; 17KB LDS; XCD-swizzled) ------
// MODE 0: qkv -> bf16 matrix [kM][2304] via 2-pass 64-row LDS transpose
// MODE 1: proj -> f32 out [kM][768] + bias
template<int MODE>
__global__ __launch_bounds__(256) void k_gemm128(const u16* __restrict__ A,
      const u16* __restrict__ wb, const float* __restrict__ bias,
      u16* __restrict__ outb, float* __restrict__ outf){
  __shared__ union SM {
    struct { u16 a[128*32]; u16 b[128*32]; } s;   // 16 KB staging
    u16 c2[64*136];                                // 17.4 KB epilogue half-tile
  } sm;
  const int wg = xcd_swz(blockIdx.x, gridDim.x);
  const int m0 = (wg % 65)*128;
  const int N0 = (wg / 65)*128;
  const int sel = (MODE==0) ? (N0/768) : 3;
  const int jb  = (MODE==0) ? (N0%768) : N0;
  const u16* W = wb + (size_t)sel*589824;
  const int t = threadIdx.x;
  const int wave = t>>6, lane = t&63;
  const int g = lane>>4, cl = lane&15;
  const int wr2 = (wave>>1)*64, wc2 = (wave&1)*64;

  const int cid0 = wave*64 + lane;
  const int cid1 = cid0 + 256;
  const int ar0 = m0 + (cid0>>2) < kM ? m0 + (cid0>>2) : kM-1;
  const int ar1 = m0 + (cid1>>2) < kM ? m0 + (cid1>>2) : kM-1;
  const int ac0 = (cid0&3)<<3, ac1 = (cid1&3)<<3;
  const int br0 = jb + (cid0>>2), br1 = jb + (cid1>>2);
  u16* lA0 = &sm.s.a[(wave*64)*8];
  u16* lA1 = &sm.s.a[(256 + wave*64)*8];
  u16* lB0 = &sm.s.b[(wave*64)*8];
  u16* lB1 = &sm.s.b[(256 + wave*64)*8];

  f32x4 acc[4][4];
  #pragma unroll
  for (int i=0;i<4;i++)
    #pragma unroll
    for (int j=0;j<4;j++) acc[i][j] = (f32x4){0.f,0.f,0.f,0.f};

  for (int k0=0; k0<768; k0+=32){
    __syncthreads();
    GLL16(A + (size_t)ar0*768 + k0 + ac0, lA0);
    GLL16(A + (size_t)ar1*768 + k0 + ac1, lA1);
    GLL16(W + (size_t)br0*768 + k0 + ac0, lB0);
    GLL16(W + (size_t)br1*768 + k0 + ac1, lB1);
    __syncthreads();
    bf16x8 af[4], bfg[4];
    #pragma unroll
    for (int fm=0; fm<4; fm++)
      af[fm] = *reinterpret_cast<const bf16x8*>(&sm.s.a[(wr2+fm*16+cl)*32 + g*8]);
    #pragma unroll
    for (int fn=0; fn<4; fn++)
      bfg[fn] = *reinterpret_cast<const bf16x8*>(&sm.s.b[(wc2+fn*16+cl)*32 + g*8]);
    #pragma unroll
    for (int fm=0; fm<4; fm++)
      #pragma unroll
      for (int fn=0; fn<4; fn++)
        acc[fm][fn] = MFMA16(af[fm], bfg[fn], acc[fm][fn]);
  }

  if (MODE==0){
    // two 64-row passes through the 17.4KB transpose buffer
    #pragma unroll
    for (int ph=0; ph<2; ++ph){
      __syncthreads();
      if ((wave>>1) == ph){
        #pragma unroll
        for (int fm=0; fm<4; fm++)
          #pragma unroll
          for (int fn=0; fn<4; fn++)
            #pragma unroll
            for (int i=0;i<4;i++){
              int r = fm*16 + g*4 + i;           // row within this half
              int c = wc2 + fn*16 + cl;
              sm.c2[r*136 + c] = f2b(acc[fm][fn][i]);
            }
      }
      __syncthreads();
      #pragma unroll
      for (int it=0; it<4; it++){
        int cid = t + it*256;
        int r = cid >> 4, cc = (cid & 15) * 8;
        int gm = m0 + ph*64 + r;
        if (gm < kM){
          *reinterpret_cast<uint4*>(&outb[(size_t)gm*2304 + N0 + cc]) =
              *reinterpret_cast<const uint4*>(&sm.c2[r*136 + cc]);
        }
      }
    }
  } else {
    #pragma unroll
    for (int fm=0; fm<4; fm++)
      #pragma unroll
      for (int fn=0; fn<4; fn++)
        #pragma unroll
        for (int i=0;i<4;i++){
          int gm = m0 + wr2 + fm*16 + g*4 + i;
          if (gm >= kM) continue;
          int gc = jb + wc2 + fn*16 + cl;
          outf[(size_t)gm*768 + gc] = acc[fm][fn][i] + bias[gc];
        }
  }
}

// ---------------- depthwise pool + LN; block = (bh, 64-np slab, which) -------
// XCD-swizzled so each XCD owns bh 12-block range (same mapping as k_attn).
__global__ __launch_bounds__(256) void k_pool3(const u16* __restrict__ qkvmat,
    const float* __restrict__ wq, const float* __restrict__ wk, const float* __restrict__ wv,
    const float* __restrict__ gq, const float* __restrict__ bq,
    const float* __restrict__ gk, const float* __restrict__ bk,
    const float* __restrict__ gv, const float* __restrict__ bv,
    u16* __restrict__ Qp, u16* __restrict__ Kp, u16* __restrict__ Vt){
  __shared__ u16 vt[64][72];                 // 9216 B, 16B-aligned rows
  const int which = blockIdx.y;
  const float* w9 = (which==0)?wq:(which==1)?wk:wv;
  const float* gg = (which==0)?gq:(which==1)?gk:gv;
  const float* bb2= (which==0)?bq:(which==1)?bk:bv;
  u16* out = (which==0)?Qp:(which==1)?Kp:Vt;

  const int wave = threadIdx.x>>6, d = threadIdx.x&63;
  const int wg  = xcd_swz(blockIdx.x, 96*17);   // 1632 % 8 == 0
  const int nb  = wg % 17;
  const int bh  = wg / 17;
  const int b = bh/12, h = bh - b*12;
  const int np0 = nb*64;
  const u16* base = qkvmat + ((size_t)b*1025)*2304 + which*768 + h*64;

  float wreg[9];
  #pragma unroll
  for (int j=0;j<9;j++) wreg[j] = w9[d*9+j];
  const float gd = gg[d], bd = bb2[d];

  for (int iter=0; iter<16; ++iter){
    const int np = np0 + iter*4 + wave;
    float v = 0.f;
    if (np < kN){
      if (np == 0){
        v = b2f(base[d]);
      } else {
        int y = (np-1)>>5, x = (np-1)&31;
        #pragma unroll
        for (int ky=0; ky<3; ky++){
          int yy = y+ky-1;
          if (yy<0 || yy>31) continue;
          #pragma unroll
          for (int kx=0; kx<3; kx++){
            int xx = x+kx-1;
            if (xx<0 || xx>31) continue;
            v += wreg[ky*3+kx] * b2f(base[(size_t)(1+yy*32+xx)*2304 + d]);
          }
        }
      }
      float s = v, s2 = v*v;
      #pragma unroll
      for (int off=1; off<64; off<<=1){ s += __shfl_xor(s, off); s2 += __shfl_xor(s2, off); }
      float mean = s*(1.f/64.f);
      float var  = s2*(1.f/64.f) - mean*mean;
      v = (v-mean)*rsqrtf(var+1e-5f)*gd + bd;
    }
    if (which==2) vt[d][iter*4+wave] = f2b(v);
    else if (np < kNP) out[((size_t)bh*kNP + np)*kD + d] = f2b(v);
  }

  if (which==2){
    __syncthreads();
    const int dr = threadIdx.x>>2, seg = threadIdx.x&3;
    if (np0 + seg*16 < kNP){
      u16* dst = Vt + ((size_t)bh*kD + dr)*kNP + np0 + seg*16;
      *reinterpret_cast<uint4*>(dst)     = *reinterpret_cast<const uint4*>(&vt[dr][seg*16]);
      *reinterpret_cast<uint4*>(dst + 8) = *reinterpret_cast<const uint4*>(&vt[dr][seg*16+8]);
    }
  }
}

// ---------------- attention: single QK^T pass + LDS e-tile ----------------
// |logit| <= 8 (LN'd q,k): no max pass. masked rows -> uniform 1/1025.
// XCD-chunked: all 65 q-tiles of one bh land on one XCD (K/V L2-resident).
__global__ __launch_bounds__(256) void k_attn(const u16* __restrict__ Qp, const u16* __restrict__ Kp,
    const u16* __restrict__ Vt, const int* __restrict__ maskn,
    float* __restrict__ attn_out, u16* __restrict__ ctx){
  constexpr int LDE = 1064;
  __shared__ u16 E[16*LDE];
  __shared__ float Lrow[16];
  __shared__ float Linv[16];
  const int wave = threadIdx.x>>6, lane = threadIdx.x&63;
  const int xcd  = blockIdx.x & 7;
  const int slot = blockIdx.x >> 3;          // 0..779
  const int bh = xcd*12 + slot/65;
  const int qt = slot%65;
  const int b  = bh / 12, h = bh - b*12;
  const int qbase = qt*16;
  const int g = lane>>4, cl = lane&15;

  if (threadIdx.x < 16) Lrow[threadIdx.x] = 0.f;
  __syncthreads();

  const u16* qrow = Qp + ((size_t)bh*kNP + (qbase + cl))*kD + g*8;
  bf16x8 aq0 = *reinterpret_cast<const bf16x8*>(qrow);
  bf16x8 aq1 = *reinterpret_cast<const bf16x8*>(qrow + 32);

  float mq[4];
  #pragma unroll
  for (int i=0;i<4;i++){
    int qi = qbase + g*4 + i;
    mq[i] = (qi<kN && maskn[b*kN+qi]!=0) ? kScale : 0.f;
  }

  // ---- phase 1: QK^T -> e -> LDS, row sums ----
  const u16* kb = Kp + (size_t)bh*kNP*kD;
  float rsum[4] = {0.f,0.f,0.f,0.f};
  #pragma unroll 2
  for (int kt=wave; kt<33; kt+=4){
    const int ktb = kt*32;
    const u16* kr = kb + (size_t)(ktb+cl)*kD + g*8;
    bf16x8 b00 = *reinterpret_cast<const bf16x8*>(kr);
    bf16x8 b01 = *reinterpret_cast<const bf16x8*>(kr+32);
    bf16x8 b10 = *reinterpret_cast<const bf16x8*>(kr+1024);
    bf16x8 b11 = *reinterpret_cast<const bf16x8*>(kr+1024+32);
    f32x4 s0 = {0.f,0.f,0.f,0.f}, s1 = {0.f,0.f,0.f,0.f};
    __builtin_amdgcn_s_setprio(1);
    s0 = MFMA16(aq0,b00,s0); s0 = MFMA16(aq1,b01,s0);
    s1 = MFMA16(aq0,b10,s1); s1 = MFMA16(aq1,b11,s1);
    __builtin_amdgcn_s_setprio(0);
    const bool v0 = (ktb+cl)<kN, v1 = (ktb+16+cl)<kN;
    #pragma unroll
    for (int i=0;i<4;i++){
      int row = g*4+i;
      float e0 = v0 ? __expf(s0[i]*mq[i]) : 0.f;
      float e1 = v1 ? __expf(s1[i]*mq[i]) : 0.f;
      rsum[i] += e0 + e1;
      E[row*LDE + ktb + cl]      = f2b(e0);
      E[row*LDE + ktb + 16 + cl] = f2b(e1);
    }
  }
  #pragma unroll
  for (int off=1; off<16; off<<=1){
    #pragma unroll
    for (int i=0;i<4;i++) rsum[i] += __shfl_xor(rsum[i], off);
  }
  if (cl == 0){
    #pragma unroll
    for (int i=0;i<4;i++) atomicAdd(&Lrow[g*4+i], rsum[i]);
  }
  __syncthreads();
  if (threadIdx.x < 16) Linv[threadIdx.x] = 1.f/Lrow[threadIdx.x];
  __syncthreads();

  // ---- phase 2a: attn tile as ONE contiguous span ----
  {
    size_t S = (size_t)bh*kN*kN + (size_t)qbase*kN;
    float* tp = attn_out + S;
    int rows = kN - qbase; if (rows > 16) rows = 16;
    int T = rows*kN;
    int head = (int)((4 - (S & 3)) & 3);
    int body4 = (T - head) >> 2;
    int tail = T - head - body4*4;
    int t = threadIdx.x;
    if (t < head){
      int e = t;
      unsigned row = ((unsigned)(e*16369))>>24;
      int col = e - (int)row*kN;
      tp[e] = b2f(E[row*LDE+col]) * Linv[row];
    }
    if (t < tail){
      int e = head + body4*4 + t;
      unsigned row = ((unsigned)(e*16369))>>24;
      int col = e - (int)row*kN;
      tp[e] = b2f(E[row*LDE+col]) * Linv[row];
    }
    for (int idx = t; idx < body4; idx += 256){
      int e = head + idx*4;
      unsigned row0 = ((unsigned)(e*16369))>>24;
      unsigned row3 = ((unsigned)((e+3)*16369))>>24;
      float4 vv;
      if (row0 == row3){
        int col = e - (int)row0*kN;
        const u16* ep = &E[row0*LDE + col];
        float li = Linv[row0];
        vv.x = b2f(ep[0])*li; vv.y = b2f(ep[1])*li;
        vv.z = b2f(ep[2])*li; vv.w = b2f(ep[3])*li;
      } else {
        float tmp[4];
        #pragma unroll
        for (int j=0;j<4;j++){
          int ee = e+j;
          unsigned row = ((unsigned)(ee*16369))>>24;
          int col = ee - (int)row*kN;
          tmp[j] = b2f(E[row*LDE+col]) * Linv[row];
        }
        vv.x=tmp[0]; vv.y=tmp[1]; vv.z=tmp[2]; vv.w=tmp[3];
      }
      *reinterpret_cast<float4*>(tp + e) = vv;
    }
  }

  // ---- phase 2b: PV, 4-deep load pipeline; wave owns 16 d-cols ----
  const int d0 = wave*16;
  f32x4 oacc = (f32x4){0.f,0.f,0.f,0.f};
  const u16* vb = Vt + ((size_t)bh*kD + d0 + cl)*kNP;
  for (int kt0=0; kt0<32; kt0+=4){
    bf16x8 pa[4], vv[4];
    #pragma unroll
    for (int j=0;j<4;j++){
      const int ko = (kt0+j)*32 + g*8;
      pa[j] = *reinterpret_cast<const bf16x8*>(&E[cl*LDE + ko]);
      vv[j] = *reinterpret_cast<const bf16x8*>(vb + ko);
    }
    __builtin_amdgcn_s_setprio(1);
    #pragma unroll
    for (int j=0;j<4;j++) oacc = MFMA16(pa[j], vv[j], oacc);
    __builtin_amdgcn_s_setprio(0);
  }
  {
    const int ko = 32*32 + g*8;
    bf16x8 pa = *reinterpret_cast<const bf16x8*>(&E[cl*LDE + ko]);
    bf16x8 vv = *reinterpret_cast<const bf16x8*>(vb + ko);
    oacc = MFMA16(pa, vv, oacc);
  }
  #pragma unroll
  for (int i=0;i<4;i++){
    int row = g*4+i, qi = qbase+row;
    if (qi < kN){
      float val = oacc[i] * Linv[row];
      int dd = d0 + cl;
      if (qi >= 1) val += b2f(Qp[((size_t)bh*kNP + qi)*kD + dd]);
      ctx[((size_t)(b*kN + qi))*kC + h*kD + dd] = f2b(val);
    }
  }
}

extern "C" void kernel_launch(void* const* d_in, const int* in_sizes, int n_in,
                              void* d_out, int out_size, void* d_ws, size_t ws_size,
                              hipStream_t stream) {
  const float* x    = (const float*)d_in[0];
  const void*  msk  = d_in[1];
  const float* Wq   = (const float*)d_in[2];
  const float* Wk   = (const float*)d_in[3];
  const float* Wv   = (const float*)d_in[4];
  const float* pw_q = (const float*)d_in[5];
  const float* pw_k = (const float*)d_in[6];
  const float* pw_v = (const float*)d_in[7];
  const float* gq   = (const float*)d_in[8];
  const float* bq   = (const float*)d_in[9];
  const float* gk   = (const float*)d_in[10];
  const float* bk   = (const float*)d_in[11];
  const float* gv   = (const float*)d_in[12];
  const float* bv   = (const float*)d_in[13];
  const float* Wp   = (const float*)d_in[14];
  const float* bp   = (const float*)d_in[15];

  char* ws = (char*)d_ws;
  u16* xb     = (u16*)(ws + 0);            // 12,595,200 B
  u16* wb     = (u16*)(ws + 12595200);     // 4,718,592 B (Wq,Wk,Wv,Wp)
  int* maskn  = (int*)(ws + 17313792);
  u16* qkvmat = (u16*)(ws + 17346816);     // [8200][2304] bf16 = 37,785,600 B
  u16* Qp     = (u16*)(ws + 55132416);
  u16* Kp     = (u16*)(ws + 68108544);
  u16* Vt     = (u16*)(ws + 81084672);
  u16* ctx    = (u16*)(ws + 17346816);     // aliases qkvmat (free after pooling)

  float* out1 = (float*)d_out;
  float* attn = out1 + (size_t)kM*kC;

  k_prep<<<8486, 256, 0, stream>>>(reinterpret_cast<const float4*>(x),
                                   Wq, Wk, Wv, Wp, (const unsigned char*)msk,
                                   xb, wb, maskn);
  k_gemm128<0><<<65*18, 256, 0, stream>>>(xb, wb, nullptr, qkvmat, nullptr);
  k_pool3<<<dim3(96*17,3), 256, 0, stream>>>(qkvmat, pw_q, pw_k, pw_v,
                                             gq, bq, gk, bk, gv, bv, Qp, Kp, Vt);
  k_attn<<<96*65, 256, 0, stream>>>(Qp, Kp, Vt, maskn, attn, ctx);
  k_gemm128<1><<<65*6, 256, 0, stream>>>(ctx, wb, bp, nullptr, out1);
}

// Round 7
// 411.511 us; speedup vs baseline: 1.1704x; 1.0019x over previous
//
#include <hip/hip_runtime.h>
#include <hip/hip_bf16.h>
#include <cstdint>
#include <cstddef>

typedef unsigned short u16;
typedef __attribute__((ext_vector_type(8))) short bf16x8;
typedef __attribute__((ext_vector_type(4))) float f32x4;

#define MFMA16(a,b,c) __builtin_amdgcn_mfma_f32_16x16x32_bf16(a,b,c,0,0,0)
#define GLL16(gp, lp) __builtin_amdgcn_global_load_lds( \
    (const __attribute__((address_space(1))) void*)(gp), \
    (__attribute__((address_space(3))) void*)(lp), 16, 0, 0)

static constexpr int kB = 8, kH = 12, kN = 1025, kC = 768, kD = 64;
static constexpr int kBH = kB*kH;          // 96
static constexpr int kNP = 1056;           // padded N (33*32)
static constexpr int kM  = kB*kN;          // 8200
static constexpr float kScale = 0.125f;

__device__ __forceinline__ u16 f2b(float f){
  unsigned u = __builtin_bit_cast(unsigned, f);
  u = (u + 0x7fffu + ((u>>16)&1u)) >> 16;
  return (u16)u;
}
__device__ __forceinline__ float b2f(u16 s){
  unsigned u = ((unsigned)s)<<16;
  return __builtin_bit_cast(float, u);
}
// bijective XCD-chunked swizzle (m204): contiguous work chunk per XCD
__device__ __forceinline__ int xcd_swz(int orig, int nwg){
  int q = nwg>>3, r = nwg&7;
  int xcd = orig&7, idx = orig>>3;
  return (xcd<r ? xcd*(q+1) : r*(q+1)+(xcd-r)*q) + idx;
}

// ---------------- fused prep: x->bf16, weights->bf16, mask normalize --------
// blocks [0,6150): conv_x ; [6150,8454): conv_w ; [8454,8486): mask
__global__ __launch_bounds__(256) void k_prep(const float4* __restrict__ x,
    const float* __restrict__ w0, const float* __restrict__ w1,
    const float* __restrict__ w2, const float* __restrict__ w3,
    const unsigned char* __restrict__ m,
    u16* __restrict__ xb, u16* __restrict__ wb, int* __restrict__ maskn){
  __shared__ int cnt;
  const int bid = blockIdx.x;
  if (bid < 6150){
    int i = bid*256 + threadIdx.x;          // exactly 1,574,400
    float4 v = x[i];
    ushort4 o; o.x=f2b(v.x); o.y=f2b(v.y); o.z=f2b(v.z); o.w=f2b(v.w);
    *reinterpret_cast<ushort4*>(xb + (size_t)i*4) = o;
  } else if (bid < 8454){
    int j = (bid-6150)*256 + threadIdx.x;   // exactly 589,824
    int sel = j/147456, i = j - sel*147456;
    const float* ws[4] = {w0,w1,w2,w3};
    float4 v = reinterpret_cast<const float4*>(ws[sel])[i];
    ushort4 o; o.x=f2b(v.x); o.y=f2b(v.y); o.z=f2b(v.z); o.w=f2b(v.w);
    *reinterpret_cast<ushort4*>(wb + (size_t)sel*589824 + (size_t)i*4) = o;
  } else {
    // mask dtype detect (bool8 vs int32/f32) on first 1024 bytes, then slice
    if (threadIdx.x==0) cnt = 0;
    __syncthreads();
    int local = 0;
    for (int i=threadIdx.x; i<1024; i+=256) local += (m[i]!=0);
    atomicAdd(&cnt, local);
    __syncthreads();
    bool b8 = (cnt > 512);
    int lb = bid - 8454;                    // 0..31
    for (int i = lb*256 + threadIdx.x; i < kM; i += 32*256){
      int v = b8 ? (m[i]!=0) : (reinterpret_cast<const int*>(m)[i] != 0);
      maskn[i] = v;
    }
  }
}

// ---------------- 128x128 GEMM (m97 structure; m-inner XCD chunks) ----------
// Chunk order: consecutive wg in an XCD chunk share the 3.5MB B working set
// (L2-resident) and read each A panel exactly once -> A fetch 227MB -> 12.6MB.
// MODE 0: qkv -> bf16 matrix [kM][2304] via 2-pass 64-row LDS transpose
// MODE 1: proj -> f32 out [kM][768] + bias
template<int MODE>
__global__ __launch_bounds__(256) void k_gemm128(const u16* __restrict__ A,
      const u16* __restrict__ wb, const float* __restrict__ bias,
      u16* __restrict__ outb, float* __restrict__ outf){
  __shared__ union SM {
    struct { u16 a[128*32]; u16 b[128*32]; } s;   // 16 KB staging
    u16 c2[64*136];                                // 17.4 KB epilogue half-tile
  } sm;
  constexpr int NB = (MODE==0) ? 18 : 6;
  const int wg = xcd_swz(blockIdx.x, gridDim.x);
  const int m0 = (wg / NB)*128;                    // m-inner within chunk
  const int N0 = (wg % NB)*128;
  const int sel = (MODE==0) ? (N0/768) : 3;
  const int jb  = (MODE==0) ? (N0%768) : N0;
  const u16* W = wb + (size_t)sel*589824;
  const int t = threadIdx.x;
  const int wave = t>>6, lane = t&63;
  const int g = lane>>4, cl = lane&15;
  const int wr2 = (wave>>1)*64, wc2 = (wave&1)*64;

  const int cid0 = wave*64 + lane;
  const int cid1 = cid0 + 256;
  const int ar0 = m0 + (cid0>>2) < kM ? m0 + (cid0>>2) : kM-1;
  const int ar1 = m0 + (cid1>>2) < kM ? m0 + (cid1>>2) : kM-1;
  const int ac0 = (cid0&3)<<3, ac1 = (cid1&3)<<3;
  const int br0 = jb + (cid0>>2), br1 = jb + (cid1>>2);
  u16* lA0 = &sm.s.a[(wave*64)*8];
  u16* lA1 = &sm.s.a[(256 + wave*64)*8];
  u16* lB0 = &sm.s.b[(wave*64)*8];
  u16* lB1 = &sm.s.b[(256 + wave*64)*8];

  f32x4 acc[4][4];
  #pragma unroll
  for (int i=0;i<4;i++)
    #pragma unroll
    for (int j=0;j<4;j++) acc[i][j] = (f32x4){0.f,0.f,0.f,0.f};

  for (int k0=0; k0<768; k0+=32){
    __syncthreads();
    GLL16(A + (size_t)ar0*768 + k0 + ac0, lA0);
    GLL16(A + (size_t)ar1*768 + k0 + ac1, lA1);
    GLL16(W + (size_t)br0*768 + k0 + ac0, lB0);
    GLL16(W + (size_t)br1*768 + k0 + ac1, lB1);
    __syncthreads();
    bf16x8 af[4], bfg[4];
    #pragma unroll
    for (int fm=0; fm<4; fm++)
      af[fm] = *reinterpret_cast<const bf16x8*>(&sm.s.a[(wr2+fm*16+cl)*32 + g*8]);
    #pragma unroll
    for (int fn=0; fn<4; fn++)
      bfg[fn] = *reinterpret_cast<const bf16x8*>(&sm.s.b[(wc2+fn*16+cl)*32 + g*8]);
    #pragma unroll
    for (int fm=0; fm<4; fm++)
      #pragma unroll
      for (int fn=0; fn<4; fn++)
        acc[fm][fn] = MFMA16(af[fm], bfg[fn], acc[fm][fn]);
  }

  if (MODE==0){
    // two 64-row passes through the 17.4KB transpose buffer
    #pragma unroll
    for (int ph=0; ph<2; ++ph){
      __syncthreads();
      if ((wave>>1) == ph){
        #pragma unroll
        for (int fm=0; fm<4; fm++)
          #pragma unroll
          for (int fn=0; fn<4; fn++)
            #pragma unroll
            for (int i=0;i<4;i++){
              int r = fm*16 + g*4 + i;           // row within this half
              int c = wc2 + fn*16 + cl;
              sm.c2[r*136 + c] = f2b(acc[fm][fn][i]);
            }
      }
      __syncthreads();
      #pragma unroll
      for (int it=0; it<4; it++){
        int cid = t + it*256;
        int r = cid >> 4, cc = (cid & 15) * 8;
        int gm = m0 + ph*64 + r;
        if (gm < kM){
          *reinterpret_cast<uint4*>(&outb[(size_t)gm*2304 + N0 + cc]) =
              *reinterpret_cast<const uint4*>(&sm.c2[r*136 + cc]);
        }
      }
    }
  } else {
    #pragma unroll
    for (int fm=0; fm<4; fm++)
      #pragma unroll
      for (int fn=0; fn<4; fn++)
        #pragma unroll
        for (int i=0;i<4;i++){
          int gm = m0 + wr2 + fm*16 + g*4 + i;
          if (gm >= kM) continue;
          int gc = jb + wc2 + fn*16 + cl;
          outf[(size_t)gm*768 + gc] = acc[fm][fn][i] + bias[gc];
        }
  }
}

// ---------------- depthwise pool + LN; block = (bh, 64-np slab, which) -------
// XCD-swizzled so each XCD owns bh 12-block range (same mapping as k_attn).
__global__ __launch_bounds__(256) void k_pool3(const u16* __restrict__ qkvmat,
    const float* __restrict__ wq, const float* __restrict__ wk, const float* __restrict__ wv,
    const float* __restrict__ gq, const float* __restrict__ bq,
    const float* __restrict__ gk, const float* __restrict__ bk,
    const float* __restrict__ gv, const float* __restrict__ bv,
    u16* __restrict__ Qp, u16* __restrict__ Kp, u16* __restrict__ Vt){
  __shared__ u16 vt[64][72];                 // 9216 B, 16B-aligned rows
  const int which = blockIdx.y;
  const float* w9 = (which==0)?wq:(which==1)?wk:wv;
  const float* gg = (which==0)?gq:(which==1)?gk:gv;
  const float* bb2= (which==0)?bq:(which==1)?bk:bv;
  u16* out = (which==0)?Qp:(which==1)?Kp:Vt;

  const int wave = threadIdx.x>>6, d = threadIdx.x&63;
  const int wg  = xcd_swz(blockIdx.x, 96*17);   // 1632 % 8 == 0
  const int nb  = wg % 17;
  const int bh  = wg / 17;
  const int b = bh/12, h = bh - b*12;
  const int np0 = nb*64;
  const u16* base = qkvmat + ((size_t)b*1025)*2304 + which*768 + h*64;

  float wreg[9];
  #pragma unroll
  for (int j=0;j<9;j++) wreg[j] = w9[d*9+j];
  const float gd = gg[d], bd = bb2[d];

  for (int iter=0; iter<16; ++iter){
    const int np = np0 + iter*4 + wave;
    float v = 0.f;
    if (np < kN){
      if (np == 0){
        v = b2f(base[d]);
      } else {
        int y = (np-1)>>5, x = (np-1)&31;
        #pragma unroll
        for (int ky=0; ky<3; ky++){
          int yy = y+ky-1;
          if (yy<0 || yy>31) continue;
          #pragma unroll
          for (int kx=0; kx<3; kx++){
            int xx = x+kx-1;
            if (xx<0 || xx>31) continue;
            v += wreg[ky*3+kx] * b2f(base[(size_t)(1+yy*32+xx)*2304 + d]);
          }
        }
      }
      float s = v, s2 = v*v;
      #pragma unroll
      for (int off=1; off<64; off<<=1){ s += __shfl_xor(s, off); s2 += __shfl_xor(s2, off); }
      float mean = s*(1.f/64.f);
      float var  = s2*(1.f/64.f) - mean*mean;
      v = (v-mean)*rsqrtf(var+1e-5f)*gd + bd;
    }
    if (which==2) vt[d][iter*4+wave] = f2b(v);
    else if (np < kNP) out[((size_t)bh*kNP + np)*kD + d] = f2b(v);
  }

  if (which==2){
    __syncthreads();
    const int dr = threadIdx.x>>2, seg = threadIdx.x&3;
    if (np0 + seg*16 < kNP){
      u16* dst = Vt + ((size_t)bh*kD + dr)*kNP + np0 + seg*16;
      *reinterpret_cast<uint4*>(dst)     = *reinterpret_cast<const uint4*>(&vt[dr][seg*16]);
      *reinterpret_cast<uint4*>(dst + 8) = *reinterpret_cast<const uint4*>(&vt[dr][seg*16+8]);
    }
  }
}

// ---------------- attention: single QK^T pass + LDS e-tile ----------------
// |logit| <= 8 (LN'd q,k): no max pass. masked rows -> uniform 1/1025.
// XCD-chunked: all 65 q-tiles of one bh land on one XCD (K/V L2-resident).
__global__ __launch_bounds__(256) void k_attn(const u16* __restrict__ Qp, const u16* __restrict__ Kp,
    const u16* __restrict__ Vt, const int* __restrict__ maskn,
    float* __restrict__ attn_out, u16* __restrict__ ctx){
  constexpr int LDE = 1064;
  __shared__ u16 E[16*LDE];
  __shared__ float Lrow[16];
  __shared__ float Linv[16];
  const int wave = threadIdx.x>>6, lane = threadIdx.x&63;
  const int xcd  = blockIdx.x & 7;
  const int slot = blockIdx.x >> 3;          // 0..779
  const int bh = xcd*12 + slot/65;
  const int qt = slot%65;
  const int b  = bh / 12, h = bh - b*12;
  const int qbase = qt*16;
  const int g = lane>>4, cl = lane&15;

  if (threadIdx.x < 16) Lrow[threadIdx.x] = 0.f;
  __syncthreads();

  const u16* qrow = Qp + ((size_t)bh*kNP + (qbase + cl))*kD + g*8;
  bf16x8 aq0 = *reinterpret_cast<const bf16x8*>(qrow);
  bf16x8 aq1 = *reinterpret_cast<const bf16x8*>(qrow + 32);

  float mq[4];
  #pragma unroll
  for (int i=0;i<4;i++){
    int qi = qbase + g*4 + i;
    mq[i] = (qi<kN && maskn[b*kN+qi]!=0) ? kScale : 0.f;
  }

  // ---- phase 1: QK^T -> e -> LDS, row sums ----
  const u16* kb = Kp + (size_t)bh*kNP*kD;
  float rsum[4] = {0.f,0.f,0.f,0.f};
  #pragma unroll 2
  for (int kt=wave; kt<33; kt+=4){
    const int ktb = kt*32;
    const u16* kr = kb + (size_t)(ktb+cl)*kD + g*8;
    bf16x8 b00 = *reinterpret_cast<const bf16x8*>(kr);
    bf16x8 b01 = *reinterpret_cast<const bf16x8*>(kr+32);
    bf16x8 b10 = *reinterpret_cast<const bf16x8*>(kr+1024);
    bf16x8 b11 = *reinterpret_cast<const bf16x8*>(kr+1024+32);
    f32x4 s0 = {0.f,0.f,0.f,0.f}, s1 = {0.f,0.f,0.f,0.f};
    __builtin_amdgcn_s_setprio(1);
    s0 = MFMA16(aq0,b00,s0); s0 = MFMA16(aq1,b01,s0);
    s1 = MFMA16(aq0,b10,s1); s1 = MFMA16(aq1,b11,s1);
    __builtin_amdgcn_s_setprio(0);
    const bool v0 = (ktb+cl)<kN, v1 = (ktb+16+cl)<kN;
    #pragma unroll
    for (int i=0;i<4;i++){
      int row = g*4+i;
      float e0 = v0 ? __expf(s0[i]*mq[i]) : 0.f;
      float e1 = v1 ? __expf(s1[i]*mq[i]) : 0.f;
      rsum[i] += e0 + e1;
      E[row*LDE + ktb + cl]      = f2b(e0);
      E[row*LDE + ktb + 16 + cl] = f2b(e1);
    }
  }
  #pragma unroll
  for (int off=1; off<16; off<<=1){
    #pragma unroll
    for (int i=0;i<4;i++) rsum[i] += __shfl_xor(rsum[i], off);
  }
  if (cl == 0){
    #pragma unroll
    for (int i=0;i<4;i++) atomicAdd(&Lrow[g*4+i], rsum[i]);
  }
  __syncthreads();
  if (threadIdx.x < 16) Linv[threadIdx.x] = 1.f/Lrow[threadIdx.x];
  __syncthreads();

  // ---- phase 2a: attn tile as ONE contiguous span ----
  {
    size_t S = (size_t)bh*kN*kN + (size_t)qbase*kN;
    float* tp = attn_out + S;
    int rows = kN - qbase; if (rows > 16) rows = 16;
    int T = rows*kN;
    int head = (int)((4 - (S & 3)) & 3);
    int body4 = (T - head) >> 2;
    int tail = T - head - body4*4;
    int t = threadIdx.x;
    if (t < head){
      int e = t;
      unsigned row = ((unsigned)(e*16369))>>24;
      int col = e - (int)row*kN;
      tp[e] = b2f(E[row*LDE+col]) * Linv[row];
    }
    if (t < tail){
      int e = head + body4*4 + t;
      unsigned row = ((unsigned)(e*16369))>>24;
      int col = e - (int)row*kN;
      tp[e] = b2f(E[row*LDE+col]) * Linv[row];
    }
    for (int idx = t; idx < body4; idx += 256){
      int e = head + idx*4;
      unsigned row0 = ((unsigned)(e*16369))>>24;
      unsigned row3 = ((unsigned)((e+3)*16369))>>24;
      float4 vv;
      if (row0 == row3){
        int col = e - (int)row0*kN;
        const u16* ep = &E[row0*LDE + col];
        float li = Linv[row0];
        vv.x = b2f(ep[0])*li; vv.y = b2f(ep[1])*li;
        vv.z = b2f(ep[2])*li; vv.w = b2f(ep[3])*li;
      } else {
        float tmp[4];
        #pragma unroll
        for (int j=0;j<4;j++){
          int ee = e+j;
          unsigned row = ((unsigned)(ee*16369))>>24;
          int col = ee - (int)row*kN;
          tmp[j] = b2f(E[row*LDE+col]) * Linv[row];
        }
        vv.x=tmp[0]; vv.y=tmp[1]; vv.z=tmp[2]; vv.w=tmp[3];
      }
      *reinterpret_cast<float4*>(tp + e) = vv;
    }
  }

  // ---- phase 2b: PV, 4-deep load pipeline; wave owns 16 d-cols ----
  const int d0 = wave*16;
  f32x4 oacc = (f32x4){0.f,0.f,0.f,0.f};
  const u16* vb = Vt + ((size_t)bh*kD + d0 + cl)*kNP;
  for (int kt0=0; kt0<32; kt0+=4){
    bf16x8 pa[4], vv[4];
    #pragma unroll
    for (int j=0;j<4;j++){
      const int ko = (kt0+j)*32 + g*8;
      pa[j] = *reinterpret_cast<const bf16x8*>(&E[cl*LDE + ko]);
      vv[j] = *reinterpret_cast<const bf16x8*>(vb + ko);
    }
    __builtin_amdgcn_s_setprio(1);
    #pragma unroll
    for (int j=0;j<4;j++) oacc = MFMA16(pa[j], vv[j], oacc);
    __builtin_amdgcn_s_setprio(0);
  }
  {
    const int ko = 32*32 + g*8;
    bf16x8 pa = *reinterpret_cast<const bf16x8*>(&E[cl*LDE + ko]);
    bf16x8 vv = *reinterpret_cast<const bf16x8*>(vb + ko);
    oacc = MFMA16(pa, vv, oacc);
  }
  #pragma unroll
  for (int i=0;i<4;i++){
    int row = g*4+i, qi = qbase+row;
    if (qi < kN){
      float val = oacc[i] * Linv[row];
      int dd = d0 + cl;
      if (qi >= 1) val += b2f(Qp[((size_t)bh*kNP + qi)*kD + dd]);
      ctx[((size_t)(b*kN + qi))*kC + h*kD + dd] = f2b(val);
    }
  }
}

extern "C" void kernel_launch(void* const* d_in, const int* in_sizes, int n_in,
                              void* d_out, int out_size, void* d_ws, size_t ws_size,
                              hipStream_t stream) {
  const float* x    = (const float*)d_in[0];
  const void*  msk  = d_in[1];
  const float* Wq   = (const float*)d_in[2];
  const float* Wk   = (const float*)d_in[3];
  const float* Wv   = (const float*)d_in[4];
  const float* pw_q = (const float*)d_in[5];
  const float* pw_k = (const float*)d_in[6];
  const float* pw_v = (const float*)d_in[7];
  const float* gq   = (const float*)d_in[8];
  const float* bq   = (const float*)d_in[9];
  const float* gk   = (const float*)d_in[10];
  const float* bk   = (const float*)d_in[11];
  const float* gv   = (const float*)d_in[12];
  const float* bv   = (const float*)d_in[13];
  const float* Wp   = (const float*)d_in[14];
  const float* bp   = (const float*)d_in[15];

  char* ws = (char*)d_ws;
  u16* xb     = (u16*)(ws + 0);            // 12,595,200 B
  u16* wb     = (u16*)(ws + 12595200);     // 4,718,592 B (Wq,Wk,Wv,Wp)
  int* maskn  = (int*)(ws + 17313792);
  u16* qkvmat = (u16*)(ws + 17346816);     // [8200][2304] bf16 = 37,785,600 B
  u16* Qp     = (u16*)(ws + 55132416);
  u16* Kp     = (u16*)(ws + 68108544);
  u16* Vt     = (u16*)(ws + 81084672);
  u16* ctx    = (u16*)(ws + 17346816);     // aliases qkvmat (free after pooling)

  float* out1 = (float*)d_out;
  float* attn = out1 + (size_t)kM*kC;

  k_prep<<<8486, 256, 0, stream>>>(reinterpret_cast<const float4*>(x),
                                   Wq, Wk, Wv, Wp, (const unsigned char*)msk,
                                   xb, wb, maskn);
  k_gemm128<0><<<65*18, 256, 0, stream>>>(xb, wb, nullptr, qkvmat, nullptr);
  k_pool3<<<dim3(96*17,3), 256, 0, stream>>>(qkvmat, pw_q, pw_k, pw_v,
                                             gq, bq, gk, bk, gv, bv, Qp, Kp, Vt);
  k_attn<<<96*65, 256, 0, stream>>>(Qp, Kp, Vt, maskn, attn, ctx);
  k_gemm128<1><<<65*6, 256, 0, stream>>>(ctx, wb, bp, nullptr, out1);
}

// Round 8
// 406.841 us; speedup vs baseline: 1.1838x; 1.0115x over previous
//
#include <hip/hip_runtime.h>
#include <hip/hip_bf16.h>
#include <cstdint>
#include <cstddef>

typedef unsigned short u16;
typedef __attribute__((ext_vector_type(8))) short bf16x8;
typedef __attribute__((ext_vector_type(4))) float f32x4;

#define MFMA16(a,b,c) __builtin_amdgcn_mfma_f32_16x16x32_bf16(a,b,c,0,0,0)
#define GLL16(gp, lp) __builtin_amdgcn_global_load_lds( \
    (const __attribute__((address_space(1))) void*)(gp), \
    (__attribute__((address_space(3))) void*)(lp), 16, 0, 0)

static constexpr int kB = 8, kH = 12, kN = 1025, kC = 768, kD = 64;
static constexpr int kBH = kB*kH;          // 96
static constexpr int kNP = 1056;           // padded N (33*32)
static constexpr int kM  = kB*kN;          // 8200
static constexpr float kScale = 0.125f;

__device__ __forceinline__ u16 f2b(float f){
  unsigned u = __builtin_bit_cast(unsigned, f);
  u = (u + 0x7fffu + ((u>>16)&1u)) >> 16;
  return (u16)u;
}
__device__ __forceinline__ float b2f(u16 s){
  unsigned u = ((unsigned)s)<<16;
  return __builtin_bit_cast(float, u);
}
// pack two f32 -> one dword of 2 bf16 (lo=a, hi=b), HW RNE (T12 recipe)
__device__ __forceinline__ unsigned pkbf(float a, float b){
  unsigned r;
  asm("v_cvt_pk_bf16_f32 %0, %1, %2" : "=v"(r) : "v"(a), "v"(b));
  return r;
}
// bijective XCD-chunked swizzle (m204): contiguous work chunk per XCD
__device__ __forceinline__ int xcd_swz(int orig, int nwg){
  int q = nwg>>3, r = nwg&7;
  int xcd = orig&7, idx = orig>>3;
  return (xcd<r ? xcd*(q+1) : r*(q+1)+(xcd-r)*q) + idx;
}

// ---------------- fused prep: x->bf16, weights->bf16, mask normalize --------
// blocks [0,6150): conv_x ; [6150,8454): conv_w ; [8454,8486): mask
__global__ __launch_bounds__(256) void k_prep(const float4* __restrict__ x,
    const float* __restrict__ w0, const float* __restrict__ w1,
    const float* __restrict__ w2, const float* __restrict__ w3,
    const unsigned char* __restrict__ m,
    u16* __restrict__ xb, u16* __restrict__ wb, int* __restrict__ maskn){
  __shared__ int cnt;
  const int bid = blockIdx.x;
  if (bid < 6150){
    int i = bid*256 + threadIdx.x;          // exactly 1,574,400
    float4 v = x[i];
    ushort4 o; o.x=f2b(v.x); o.y=f2b(v.y); o.z=f2b(v.z); o.w=f2b(v.w);
    *reinterpret_cast<ushort4*>(xb + (size_t)i*4) = o;
  } else if (bid < 8454){
    int j = (bid-6150)*256 + threadIdx.x;   // exactly 589,824
    int sel = j/147456, i = j - sel*147456;
    const float* ws[4] = {w0,w1,w2,w3};
    float4 v = reinterpret_cast<const float4*>(ws[sel])[i];
    ushort4 o; o.x=f2b(v.x); o.y=f2b(v.y); o.z=f2b(v.z); o.w=f2b(v.w);
    *reinterpret_cast<ushort4*>(wb + (size_t)sel*589824 + (size_t)i*4) = o;
  } else {
    // mask dtype detect (bool8 vs int32/f32) on first 1024 bytes, then slice
    if (threadIdx.x==0) cnt = 0;
    __syncthreads();
    int local = 0;
    for (int i=threadIdx.x; i<1024; i+=256) local += (m[i]!=0);
    atomicAdd(&cnt, local);
    __syncthreads();
    bool b8 = (cnt > 512);
    int lb = bid - 8454;                    // 0..31
    for (int i = lb*256 + threadIdx.x; i < kM; i += 32*256){
      int v = b8 ? (m[i]!=0) : (reinterpret_cast<const int*>(m)[i] != 0);
      maskn[i] = v;
    }
  }
}

// ---------------- 128x128 GEMM (m97 structure; m-inner XCD chunks) ----------
// MODE 0: qkv -> bf16 matrix [kM][2304] via 2-pass 64-row LDS transpose
// MODE 1: proj -> f32 out [kM][768] + bias
template<int MODE>
__global__ __launch_bounds__(256) void k_gemm128(const u16* __restrict__ A,
      const u16* __restrict__ wb, const float* __restrict__ bias,
      u16* __restrict__ outb, float* __restrict__ outf){
  __shared__ union SM {
    struct { u16 a[128*32]; u16 b[128*32]; } s;   // 16 KB staging
    u16 c2[64*136];                                // 17.4 KB epilogue half-tile
  } sm;
  constexpr int NB = (MODE==0) ? 18 : 6;
  const int wg = xcd_swz(blockIdx.x, gridDim.x);
  const int m0 = (wg / NB)*128;                    // m-inner within chunk
  const int N0 = (wg % NB)*128;
  const int sel = (MODE==0) ? (N0/768) : 3;
  const int jb  = (MODE==0) ? (N0%768) : N0;
  const u16* W = wb + (size_t)sel*589824;
  const int t = threadIdx.x;
  const int wave = t>>6, lane = t&63;
  const int g = lane>>4, cl = lane&15;
  const int wr2 = (wave>>1)*64, wc2 = (wave&1)*64;

  const int cid0 = wave*64 + lane;
  const int cid1 = cid0 + 256;
  const int ar0 = m0 + (cid0>>2) < kM ? m0 + (cid0>>2) : kM-1;
  const int ar1 = m0 + (cid1>>2) < kM ? m0 + (cid1>>2) : kM-1;
  const int ac0 = (cid0&3)<<3, ac1 = (cid1&3)<<3;
  const int br0 = jb + (cid0>>2), br1 = jb + (cid1>>2);
  u16* lA0 = &sm.s.a[(wave*64)*8];
  u16* lA1 = &sm.s.a[(256 + wave*64)*8];
  u16* lB0 = &sm.s.b[(wave*64)*8];
  u16* lB1 = &sm.s.b[(256 + wave*64)*8];

  f32x4 acc[4][4];
  #pragma unroll
  for (int i=0;i<4;i++)
    #pragma unroll
    for (int j=0;j<4;j++) acc[i][j] = (f32x4){0.f,0.f,0.f,0.f};

  for (int k0=0; k0<768; k0+=32){
    __syncthreads();
    GLL16(A + (size_t)ar0*768 + k0 + ac0, lA0);
    GLL16(A + (size_t)ar1*768 + k0 + ac1, lA1);
    GLL16(W + (size_t)br0*768 + k0 + ac0, lB0);
    GLL16(W + (size_t)br1*768 + k0 + ac1, lB1);
    __syncthreads();
    bf16x8 af[4], bfg[4];
    #pragma unroll
    for (int fm=0; fm<4; fm++)
      af[fm] = *reinterpret_cast<const bf16x8*>(&sm.s.a[(wr2+fm*16+cl)*32 + g*8]);
    #pragma unroll
    for (int fn=0; fn<4; fn++)
      bfg[fn] = *reinterpret_cast<const bf16x8*>(&sm.s.b[(wc2+fn*16+cl)*32 + g*8]);
    #pragma unroll
    for (int fm=0; fm<4; fm++)
      #pragma unroll
      for (int fn=0; fn<4; fn++)
        acc[fm][fn] = MFMA16(af[fm], bfg[fn], acc[fm][fn]);
  }

  if (MODE==0){
    // two 64-row passes through the 17.4KB transpose buffer
    #pragma unroll
    for (int ph=0; ph<2; ++ph){
      __syncthreads();
      if ((wave>>1) == ph){
        #pragma unroll
        for (int fm=0; fm<4; fm++)
          #pragma unroll
          for (int fn=0; fn<4; fn++)
            #pragma unroll
            for (int i=0;i<4;i++){
              int r = fm*16 + g*4 + i;           // row within this half
              int c = wc2 + fn*16 + cl;
              sm.c2[r*136 + c] = f2b(acc[fm][fn][i]);
            }
      }
      __syncthreads();
      #pragma unroll
      for (int it=0; it<4; it++){
        int cid = t + it*256;
        int r = cid >> 4, cc = (cid & 15) * 8;
        int gm = m0 + ph*64 + r;
        if (gm < kM){
          *reinterpret_cast<uint4*>(&outb[(size_t)gm*2304 + N0 + cc]) =
              *reinterpret_cast<const uint4*>(&sm.c2[r*136 + cc]);
        }
      }
    }
  } else {
    #pragma unroll
    for (int fm=0; fm<4; fm++)
      #pragma unroll
      for (int fn=0; fn<4; fn++)
        #pragma unroll
        for (int i=0;i<4;i++){
          int gm = m0 + wr2 + fm*16 + g*4 + i;
          if (gm >= kM) continue;
          int gc = jb + wc2 + fn*16 + cl;
          outf[(size_t)gm*768 + gc] = acc[fm][fn][i] + bias[gc];
        }
  }
}

// ---------------- depthwise pool + LN; block = (bh, 64-np slab, which) -------
__global__ __launch_bounds__(256) void k_pool3(const u16* __restrict__ qkvmat,
    const float* __restrict__ wq, const float* __restrict__ wk, const float* __restrict__ wv,
    const float* __restrict__ gq, const float* __restrict__ bq,
    const float* __restrict__ gk, const float* __restrict__ bk,
    const float* __restrict__ gv, const float* __restrict__ bv,
    u16* __restrict__ Qp, u16* __restrict__ Kp, u16* __restrict__ Vt){
  __shared__ u16 vt[64][72];                 // 9216 B, 16B-aligned rows
  const int which = blockIdx.y;
  const float* w9 = (which==0)?wq:(which==1)?wk:wv;
  const float* gg = (which==0)?gq:(which==1)?gk:gv;
  const float* bb2= (which==0)?bq:(which==1)?bk:bv;
  u16* out = (which==0)?Qp:(which==1)?Kp:Vt;

  const int wave = threadIdx.x>>6, d = threadIdx.x&63;
  const int wg  = xcd_swz(blockIdx.x, 96*17);   // 1632 % 8 == 0
  const int nb  = wg % 17;
  const int bh  = wg / 17;
  const int b = bh/12, h = bh - b*12;
  const int np0 = nb*64;
  const u16* base = qkvmat + ((size_t)b*1025)*2304 + which*768 + h*64;

  float wreg[9];
  #pragma unroll
  for (int j=0;j<9;j++) wreg[j] = w9[d*9+j];
  const float gd = gg[d], bd = bb2[d];

  for (int iter=0; iter<16; ++iter){
    const int np = np0 + iter*4 + wave;
    float v = 0.f;
    if (np < kN){
      if (np == 0){
        v = b2f(base[d]);
      } else {
        int y = (np-1)>>5, x = (np-1)&31;
        #pragma unroll
        for (int ky=0; ky<3; ky++){
          int yy = y+ky-1;
          if (yy<0 || yy>31) continue;
          #pragma unroll
          for (int kx=0; kx<3; kx++){
            int xx = x+kx-1;
            if (xx<0 || xx>31) continue;
            v += wreg[ky*3+kx] * b2f(base[(size_t)(1+yy*32+xx)*2304 + d]);
          }
        }
      }
      float s = v, s2 = v*v;
      #pragma unroll
      for (int off=1; off<64; off<<=1){ s += __shfl_xor(s, off); s2 += __shfl_xor(s2, off); }
      float mean = s*(1.f/64.f);
      float var  = s2*(1.f/64.f) - mean*mean;
      v = (v-mean)*rsqrtf(var+1e-5f)*gd + bd;
    }
    if (which==2) vt[d][iter*4+wave] = f2b(v);
    else if (np < kNP) out[((size_t)bh*kNP + np)*kD + d] = f2b(v);
  }

  if (which==2){
    __syncthreads();
    const int dr = threadIdx.x>>2, seg = threadIdx.x&3;
    if (np0 + seg*16 < kNP){
      u16* dst = Vt + ((size_t)bh*kD + dr)*kNP + np0 + seg*16;
      *reinterpret_cast<uint4*>(dst)     = *reinterpret_cast<const uint4*>(&vt[dr][seg*16]);
      *reinterpret_cast<uint4*>(dst + 8) = *reinterpret_cast<const uint4*>(&vt[dr][seg*16+8]);
    }
  }
}

// ---------------- attention: swapped-QK^T single pass + LDS e-tile ----------
// S^T = mfma(K_frag, Q_frag): lane holds 1 q-row x 4 consecutive k-cols ->
// pk-pack + ds_write_b64, no per-col masks in main loop (kt=32 peeled).
// |logit| <= 8 (LN'd q,k): no max pass. masked rows -> uniform 1/1025.
__global__ __launch_bounds__(256) void k_attn(const u16* __restrict__ Qp, const u16* __restrict__ Kp,
    const u16* __restrict__ Vt, const int* __restrict__ maskn,
    float* __restrict__ attn_out, u16* __restrict__ ctx){
  constexpr int LDE = 1064;
  __shared__ u16 E[16*LDE];
  __shared__ float Lrow[16];
  __shared__ float Linv[16];
  const int wave = threadIdx.x>>6, lane = threadIdx.x&63;
  const int xcd  = blockIdx.x & 7;
  const int slot = blockIdx.x >> 3;          // 0..779
  const int bh = xcd*12 + slot/65;
  const int qt = slot%65;
  const int b  = bh / 12, h = bh - b*12;
  const int qbase = qt*16;
  const int g = lane>>4, cl = lane&15;

  if (threadIdx.x < 16) Lrow[threadIdx.x] = 0.f;
  __syncthreads();

  const u16* qrow = Qp + ((size_t)bh*kNP + (qbase + cl))*kD + g*8;
  bf16x8 aq0 = *reinterpret_cast<const bf16x8*>(qrow);
  bf16x8 aq1 = *reinterpret_cast<const bf16x8*>(qrow + 32);

  // per-lane row mask*scale (one scalar: lane owns q-row = cl)
  const int qi_l = qbase + cl;
  const float mqc = (qi_l < kN && maskn[b*kN + qi_l] != 0) ? kScale : 0.f;

  // ---- phase 1: S^T = mfma(K,Q) -> e -> packed b64 LDS writes, row sums ----
  const u16* kb = Kp + (size_t)bh*kNP*kD;
  float rsum = 0.f;
  u16* erow = &E[cl*LDE];
  #pragma unroll 2
  for (int kt=wave; kt<32; kt+=4){
    const int ktb = kt*32;
    const u16* kr = kb + (size_t)(ktb+cl)*kD + g*8;
    bf16x8 b00 = *reinterpret_cast<const bf16x8*>(kr);
    bf16x8 b01 = *reinterpret_cast<const bf16x8*>(kr+32);
    bf16x8 b10 = *reinterpret_cast<const bf16x8*>(kr+1024);
    bf16x8 b11 = *reinterpret_cast<const bf16x8*>(kr+1024+32);
    f32x4 s0 = {0.f,0.f,0.f,0.f}, s1 = {0.f,0.f,0.f,0.f};
    __builtin_amdgcn_s_setprio(1);
    s0 = MFMA16(b00,aq0,s0); s0 = MFMA16(b01,aq1,s0);   // swapped: S^T rows=k
    s1 = MFMA16(b10,aq0,s1); s1 = MFMA16(b11,aq1,s1);
    __builtin_amdgcn_s_setprio(0);
    float e0 = __expf(s0[0]*mqc), e1 = __expf(s0[1]*mqc);
    float e2 = __expf(s0[2]*mqc), e3 = __expf(s0[3]*mqc);
    float f0 = __expf(s1[0]*mqc), f1 = __expf(s1[1]*mqc);
    float f2 = __expf(s1[2]*mqc), f3 = __expf(s1[3]*mqc);
    rsum += ((e0+e1)+(e2+e3)) + ((f0+f1)+(f2+f3));
    uint2 w0v = { pkbf(e0,e1), pkbf(e2,e3) };
    uint2 w1v = { pkbf(f0,f1), pkbf(f2,f3) };
    *reinterpret_cast<uint2*>(&erow[ktb + 4*g])      = w0v;
    *reinterpret_cast<uint2*>(&erow[ktb + 16 + 4*g]) = w1v;
  }
  if (wave == 0){
    // kt = 32 boundary tile: only col 1024 (g==0, elem 0) is valid
    const int ktb = 1024;
    const u16* kr = kb + (size_t)(ktb+cl)*kD + g*8;
    bf16x8 b00 = *reinterpret_cast<const bf16x8*>(kr);
    bf16x8 b01 = *reinterpret_cast<const bf16x8*>(kr+32);
    f32x4 s0 = {0.f,0.f,0.f,0.f};
    s0 = MFMA16(b00,aq0,s0); s0 = MFMA16(b01,aq1,s0);
    float e0 = (g==0) ? __expf(s0[0]*mqc) : 0.f;
    rsum += e0;
    uint2 w0v = { pkbf(e0,0.f), 0u };
    uint2 zz  = { 0u, 0u };
    *reinterpret_cast<uint2*>(&erow[ktb + 4*g])      = w0v;
    *reinterpret_cast<uint2*>(&erow[ktb + 16 + 4*g]) = zz;
  }
  // reduce across the 4 g-lanes holding each row, one atomic per row per wave
  rsum += __shfl_xor(rsum, 16);
  rsum += __shfl_xor(rsum, 32);
  if (lane < 16) atomicAdd(&Lrow[cl], rsum);
  __syncthreads();
  if (threadIdx.x < 16) Linv[threadIdx.x] = 1.f/Lrow[threadIdx.x];
  __syncthreads();

  // ---- phase 2a: attn tile as ONE contiguous span ----
  {
    size_t S = (size_t)bh*kN*kN + (size_t)qbase*kN;
    float* tp = attn_out + S;
    int rows = kN - qbase; if (rows > 16) rows = 16;
    int T = rows*kN;
    int head = (int)((4 - (S & 3)) & 3);
    int body4 = (T - head) >> 2;
    int tail = T - head - body4*4;
    int t = threadIdx.x;
    if (t < head){
      int e = t;
      unsigned row = ((unsigned)(e*16369))>>24;
      int col = e - (int)row*kN;
      tp[e] = b2f(E[row*LDE+col]) * Linv[row];
    }
    if (t < tail){
      int e = head + body4*4 + t;
      unsigned row = ((unsigned)(e*16369))>>24;
      int col = e - (int)row*kN;
      tp[e] = b2f(E[row*LDE+col]) * Linv[row];
    }
    for (int idx = t; idx < body4; idx += 256){
      int e = head + idx*4;
      unsigned row0 = ((unsigned)(e*16369))>>24;
      unsigned row3 = ((unsigned)((e+3)*16369))>>24;
      float4 vv;
      if (row0 == row3){
        int col = e - (int)row0*kN;
        const u16* ep = &E[row0*LDE + col];
        float li = Linv[row0];
        vv.x = b2f(ep[0])*li; vv.y = b2f(ep[1])*li;
        vv.z = b2f(ep[2])*li; vv.w = b2f(ep[3])*li;
      } else {
        float tmp[4];
        #pragma unroll
        for (int j=0;j<4;j++){
          int ee = e+j;
          unsigned row = ((unsigned)(ee*16369))>>24;
          int col = ee - (int)row*kN;
          tmp[j] = b2f(E[row*LDE+col]) * Linv[row];
        }
        vv.x=tmp[0]; vv.y=tmp[1]; vv.z=tmp[2]; vv.w=tmp[3];
      }
      *reinterpret_cast<float4*>(tp + e) = vv;
    }
  }

  // ---- phase 2b: PV, 4-deep load pipeline; wave owns 16 d-cols ----
  const int d0 = wave*16;
  f32x4 oacc = (f32x4){0.f,0.f,0.f,0.f};
  const u16* vb = Vt + ((size_t)bh*kD + d0 + cl)*kNP;
  for (int kt0=0; kt0<32; kt0+=4){
    bf16x8 pa[4], vv[4];
    #pragma unroll
    for (int j=0;j<4;j++){
      const int ko = (kt0+j)*32 + g*8;
      pa[j] = *reinterpret_cast<const bf16x8*>(&E[cl*LDE + ko]);
      vv[j] = *reinterpret_cast<const bf16x8*>(vb + ko);
    }
    __builtin_amdgcn_s_setprio(1);
    #pragma unroll
    for (int j=0;j<4;j++) oacc = MFMA16(pa[j], vv[j], oacc);
    __builtin_amdgcn_s_setprio(0);
  }
  {
    const int ko = 32*32 + g*8;
    bf16x8 pa = *reinterpret_cast<const bf16x8*>(&E[cl*LDE + ko]);
    bf16x8 vv = *reinterpret_cast<const bf16x8*>(vb + ko);
    oacc = MFMA16(pa, vv, oacc);
  }
  #pragma unroll
  for (int i=0;i<4;i++){
    int row = g*4+i, qi = qbase+row;
    if (qi < kN){
      float val = oacc[i] * Linv[row];
      int dd = d0 + cl;
      if (qi >= 1) val += b2f(Qp[((size_t)bh*kNP + qi)*kD + dd]);
      ctx[((size_t)(b*kN + qi))*kC + h*kD + dd] = f2b(val);
    }
  }
}

extern "C" void kernel_launch(void* const* d_in, const int* in_sizes, int n_in,
                              void* d_out, int out_size, void* d_ws, size_t ws_size,
                              hipStream_t stream) {
  const float* x    = (const float*)d_in[0];
  const void*  msk  = d_in[1];
  const float* Wq   = (const float*)d_in[2];
  const float* Wk   = (const float*)d_in[3];
  const float* Wv   = (const float*)d_in[4];
  const float* pw_q = (const float*)d_in[5];
  const float* pw_k = (const float*)d_in[6];
  const float* pw_v = (const float*)d_in[7];
  const float* gq   = (const float*)d_in[8];
  const float* bq   = (const float*)d_in[9];
  const float* gk   = (const float*)d_in[10];
  const float* bk   = (const float*)d_in[11];
  const float* gv   = (const float*)d_in[12];
  const float* bv   = (const float*)d_in[13];
  const float* Wp   = (const float*)d_in[14];
  const float* bp   = (const float*)d_in[15];

  char* ws = (char*)d_ws;
  u16* xb     = (u16*)(ws + 0);            // 12,595,200 B
  u16* wb     = (u16*)(ws + 12595200);     // 4,718,592 B (Wq,Wk,Wv,Wp)
  int* maskn  = (int*)(ws + 17313792);
  u16* qkvmat = (u16*)(ws + 17346816);     // [8200][2304] bf16 = 37,785,600 B
  u16* Qp     = (u16*)(ws + 55132416);
  u16* Kp     = (u16*)(ws + 68108544);
  u16* Vt     = (u16*)(ws + 81084672);
  u16* ctx    = (u16*)(ws + 17346816);     // aliases qkvmat (free after pooling)

  float* out1 = (float*)d_out;
  float* attn = out1 + (size_t)kM*kC;

  k_prep<<<8486, 256, 0, stream>>>(reinterpret_cast<const float4*>(x),
                                   Wq, Wk, Wv, Wp, (const unsigned char*)msk,
                                   xb, wb, maskn);
  k_gemm128<0><<<65*18, 256, 0, stream>>>(xb, wb, nullptr, qkvmat, nullptr);
  k_pool3<<<dim3(96*17,3), 256, 0, stream>>>(qkvmat, pw_q, pw_k, pw_v,
                                             gq, bq, gk, bk, gv, bv, Qp, Kp, Vt);
  k_attn<<<96*65, 256, 0, stream>>>(Qp, Kp, Vt, maskn, attn, ctx);
  k_gemm128<1><<<65*6, 256, 0, stream>>>(ctx, wb, bp, nullptr, out1);
}

// Round 9
// 395.878 us; speedup vs baseline: 1.2166x; 1.0277x over previous
//
#include <hip/hip_runtime.h>
#include <hip/hip_bf16.h>
#include <cstdint>
#include <cstddef>

typedef unsigned short u16;
typedef __attribute__((ext_vector_type(8))) short bf16x8;
typedef __attribute__((ext_vector_type(4))) float f32x4;

#define MFMA16(a,b,c) __builtin_amdgcn_mfma_f32_16x16x32_bf16(a,b,c,0,0,0)
#define GLL16(gp, lp) __builtin_amdgcn_global_load_lds( \
    (const __attribute__((address_space(1))) void*)(gp), \
    (__attribute__((address_space(3))) void*)(lp), 16, 0, 0)

static constexpr int kB = 8, kH = 12, kN = 1025, kC = 768, kD = 64;
static constexpr int kBH = kB*kH;          // 96
static constexpr int kNP = 1056;           // padded N (33*32)
static constexpr int kM  = kB*kN;          // 8200
static constexpr float kScale = 0.125f;

__device__ __forceinline__ u16 f2b(float f){
  unsigned u = __builtin_bit_cast(unsigned, f);
  u = (u + 0x7fffu + ((u>>16)&1u)) >> 16;
  return (u16)u;
}
__device__ __forceinline__ float b2f(u16 s){
  unsigned u = ((unsigned)s)<<16;
  return __builtin_bit_cast(float, u);
}
// pack two f32 -> one dword of 2 bf16 (lo=a, hi=b), HW RNE (T12 recipe)
__device__ __forceinline__ unsigned pkbf(float a, float b){
  unsigned r;
  asm("v_cvt_pk_bf16_f32 %0, %1, %2" : "=v"(r) : "v"(a), "v"(b));
  return r;
}
// bijective XCD-chunked swizzle (m204): contiguous work chunk per XCD
__device__ __forceinline__ int xcd_swz(int orig, int nwg){
  int q = nwg>>3, r = nwg&7;
  int xcd = orig&7, idx = orig>>3;
  return (xcd<r ? xcd*(q+1) : r*(q+1)+(xcd-r)*q) + idx;
}

// ---------------- fused prep: x->bf16, weights->bf16, mask normalize --------
// blocks [0,6150): conv_x ; [6150,8454): conv_w ; [8454,8486): mask
__global__ __launch_bounds__(256) void k_prep(const float4* __restrict__ x,
    const float* __restrict__ w0, const float* __restrict__ w1,
    const float* __restrict__ w2, const float* __restrict__ w3,
    const unsigned char* __restrict__ m,
    u16* __restrict__ xb, u16* __restrict__ wb, int* __restrict__ maskn){
  __shared__ int cnt;
  const int bid = blockIdx.x;
  if (bid < 6150){
    int i = bid*256 + threadIdx.x;          // exactly 1,574,400
    float4 v = x[i];
    ushort4 o; o.x=f2b(v.x); o.y=f2b(v.y); o.z=f2b(v.z); o.w=f2b(v.w);
    *reinterpret_cast<ushort4*>(xb + (size_t)i*4) = o;
  } else if (bid < 8454){
    int j = (bid-6150)*256 + threadIdx.x;   // exactly 589,824
    int sel = j/147456, i = j - sel*147456;
    const float* ws[4] = {w0,w1,w2,w3};
    float4 v = reinterpret_cast<const float4*>(ws[sel])[i];
    ushort4 o; o.x=f2b(v.x); o.y=f2b(v.y); o.z=f2b(v.z); o.w=f2b(v.w);
    *reinterpret_cast<ushort4*>(wb + (size_t)sel*589824 + (size_t)i*4) = o;
  } else {
    // mask dtype detect (bool8 vs int32/f32) on first 1024 bytes, then slice
    if (threadIdx.x==0) cnt = 0;
    __syncthreads();
    int local = 0;
    for (int i=threadIdx.x; i<1024; i+=256) local += (m[i]!=0);
    atomicAdd(&cnt, local);
    __syncthreads();
    bool b8 = (cnt > 512);
    int lb = bid - 8454;                    // 0..31
    for (int i = lb*256 + threadIdx.x; i < kM; i += 32*256){
      int v = b8 ? (m[i]!=0) : (reinterpret_cast<const int*>(m)[i] != 0);
      maskn[i] = v;
    }
  }
}

// ---------------- 128x128 GEMM (m97 structure; m-inner XCD chunks) ----------
// MODE 0: qkv -> bf16 matrix [kM][2304] via 2-pass 64-row LDS transpose
// MODE 1: proj -> f32 out [kM][768] + bias
template<int MODE>
__global__ __launch_bounds__(256) void k_gemm128(const u16* __restrict__ A,
      const u16* __restrict__ wb, const float* __restrict__ bias,
      u16* __restrict__ outb, float* __restrict__ outf){
  __shared__ union SM {
    struct { u16 a[128*32]; u16 b[128*32]; } s;   // 16 KB staging
    u16 c2[64*136];                                // 17.4 KB epilogue half-tile
  } sm;
  constexpr int NB = (MODE==0) ? 18 : 6;
  const int wg = xcd_swz(blockIdx.x, gridDim.x);
  const int m0 = (wg / NB)*128;                    // m-inner within chunk
  const int N0 = (wg % NB)*128;
  const int sel = (MODE==0) ? (N0/768) : 3;
  const int jb  = (MODE==0) ? (N0%768) : N0;
  const u16* W = wb + (size_t)sel*589824;
  const int t = threadIdx.x;
  const int wave = t>>6, lane = t&63;
  const int g = lane>>4, cl = lane&15;
  const int wr2 = (wave>>1)*64, wc2 = (wave&1)*64;

  const int cid0 = wave*64 + lane;
  const int cid1 = cid0 + 256;
  const int ar0 = m0 + (cid0>>2) < kM ? m0 + (cid0>>2) : kM-1;
  const int ar1 = m0 + (cid1>>2) < kM ? m0 + (cid1>>2) : kM-1;
  const int ac0 = (cid0&3)<<3, ac1 = (cid1&3)<<3;
  const int br0 = jb + (cid0>>2), br1 = jb + (cid1>>2);
  u16* lA0 = &sm.s.a[(wave*64)*8];
  u16* lA1 = &sm.s.a[(256 + wave*64)*8];
  u16* lB0 = &sm.s.b[(wave*64)*8];
  u16* lB1 = &sm.s.b[(256 + wave*64)*8];

  f32x4 acc[4][4];
  #pragma unroll
  for (int i=0;i<4;i++)
    #pragma unroll
    for (int j=0;j<4;j++) acc[i][j] = (f32x4){0.f,0.f,0.f,0.f};

  for (int k0=0; k0<768; k0+=32){
    __syncthreads();
    GLL16(A + (size_t)ar0*768 + k0 + ac0, lA0);
    GLL16(A + (size_t)ar1*768 + k0 + ac1, lA1);
    GLL16(W + (size_t)br0*768 + k0 + ac0, lB0);
    GLL16(W + (size_t)br1*768 + k0 + ac1, lB1);
    __syncthreads();
    bf16x8 af[4], bfg[4];
    #pragma unroll
    for (int fm=0; fm<4; fm++)
      af[fm] = *reinterpret_cast<const bf16x8*>(&sm.s.a[(wr2+fm*16+cl)*32 + g*8]);
    #pragma unroll
    for (int fn=0; fn<4; fn++)
      bfg[fn] = *reinterpret_cast<const bf16x8*>(&sm.s.b[(wc2+fn*16+cl)*32 + g*8]);
    #pragma unroll
    for (int fm=0; fm<4; fm++)
      #pragma unroll
      for (int fn=0; fn<4; fn++)
        acc[fm][fn] = MFMA16(af[fm], bfg[fn], acc[fm][fn]);
  }

  if (MODE==0){
    // two 64-row passes through the 17.4KB transpose buffer
    #pragma unroll
    for (int ph=0; ph<2; ++ph){
      __syncthreads();
      if ((wave>>1) == ph){
        #pragma unroll
        for (int fm=0; fm<4; fm++)
          #pragma unroll
          for (int fn=0; fn<4; fn++)
            #pragma unroll
            for (int i=0;i<4;i++){
              int r = fm*16 + g*4 + i;           // row within this half
              int c = wc2 + fn*16 + cl;
              sm.c2[r*136 + c] = f2b(acc[fm][fn][i]);
            }
      }
      __syncthreads();
      #pragma unroll
      for (int it=0; it<4; it++){
        int cid = t + it*256;
        int r = cid >> 4, cc = (cid & 15) * 8;
        int gm = m0 + ph*64 + r;
        if (gm < kM){
          *reinterpret_cast<uint4*>(&outb[(size_t)gm*2304 + N0 + cc]) =
              *reinterpret_cast<const uint4*>(&sm.c2[r*136 + cc]);
        }
      }
    }
  } else {
    #pragma unroll
    for (int fm=0; fm<4; fm++)
      #pragma unroll
      for (int fn=0; fn<4; fn++)
        #pragma unroll
        for (int i=0;i<4;i++){
          int gm = m0 + wr2 + fm*16 + g*4 + i;
          if (gm >= kM) continue;
          int gc = jb + wc2 + fn*16 + cl;
          outf[(size_t)gm*768 + gc] = acc[fm][fn][i] + bias[gc];
        }
  }
}

// ---------------- depthwise pool + LN; block = (bh, 64-np slab, which) -------
__global__ __launch_bounds__(256) void k_pool3(const u16* __restrict__ qkvmat,
    const float* __restrict__ wq, const float* __restrict__ wk, const float* __restrict__ wv,
    const float* __restrict__ gq, const float* __restrict__ bq,
    const float* __restrict__ gk, const float* __restrict__ bk,
    const float* __restrict__ gv, const float* __restrict__ bv,
    u16* __restrict__ Qp, u16* __restrict__ Kp, u16* __restrict__ Vt){
  __shared__ u16 vt[64][72];                 // 9216 B, 16B-aligned rows
  const int which = blockIdx.y;
  const float* w9 = (which==0)?wq:(which==1)?wk:wv;
  const float* gg = (which==0)?gq:(which==1)?gk:gv;
  const float* bb2= (which==0)?bq:(which==1)?bk:bv;
  u16* out = (which==0)?Qp:(which==1)?Kp:Vt;

  const int wave = threadIdx.x>>6, d = threadIdx.x&63;
  const int wg  = xcd_swz(blockIdx.x, 96*17);   // 1632 % 8 == 0
  const int nb  = wg % 17;
  const int bh  = wg / 17;
  const int b = bh/12, h = bh - b*12;
  const int np0 = nb*64;
  const u16* base = qkvmat + ((size_t)b*1025)*2304 + which*768 + h*64;

  float wreg[9];
  #pragma unroll
  for (int j=0;j<9;j++) wreg[j] = w9[d*9+j];
  const float gd = gg[d], bd = bb2[d];

  for (int iter=0; iter<16; ++iter){
    const int np = np0 + iter*4 + wave;
    float v = 0.f;
    if (np < kN){
      if (np == 0){
        v = b2f(base[d]);
      } else {
        int y = (np-1)>>5, x = (np-1)&31;
        #pragma unroll
        for (int ky=0; ky<3; ky++){
          int yy = y+ky-1;
          if (yy<0 || yy>31) continue;
          #pragma unroll
          for (int kx=0; kx<3; kx++){
            int xx = x+kx-1;
            if (xx<0 || xx>31) continue;
            v += wreg[ky*3+kx] * b2f(base[(size_t)(1+yy*32+xx)*2304 + d]);
          }
        }
      }
      float s = v, s2 = v*v;
      #pragma unroll
      for (int off=1; off<64; off<<=1){ s += __shfl_xor(s, off); s2 += __shfl_xor(s2, off); }
      float mean = s*(1.f/64.f);
      float var  = s2*(1.f/64.f) - mean*mean;
      v = (v-mean)*rsqrtf(var+1e-5f)*gd + bd;
    }
    if (which==2) vt[d][iter*4+wave] = f2b(v);
    else if (np < kNP) out[((size_t)bh*kNP + np)*kD + d] = f2b(v);
  }

  if (which==2){
    __syncthreads();
    const int dr = threadIdx.x>>2, seg = threadIdx.x&3;
    if (np0 + seg*16 < kNP){
      u16* dst = Vt + ((size_t)bh*kD + dr)*kNP + np0 + seg*16;
      *reinterpret_cast<uint4*>(dst)     = *reinterpret_cast<const uint4*>(&vt[dr][seg*16]);
      *reinterpret_cast<uint4*>(dst + 8) = *reinterpret_cast<const uint4*>(&vt[dr][seg*16+8]);
    }
  }
}

// ---------------- attention: 512-thread, role-split phase 2 -----------------
// phase 1 (8 waves): swapped S^T=mfma(K,Q) -> e -> LDS, row sums.
// phase 2: waves 0-3 PV + ctx; waves 4-7 attn store (overlapped).
// |logit| <= 8 (LN'd q,k): no max pass. masked rows -> uniform 1/1025.
__global__ __launch_bounds__(512, 8) void k_attn(const u16* __restrict__ Qp, const u16* __restrict__ Kp,
    const u16* __restrict__ Vt, const int* __restrict__ maskn,
    float* __restrict__ attn_out, u16* __restrict__ ctx){
  constexpr int LDE = 1064;
  __shared__ u16 E[16*LDE];
  __shared__ float Lrow[16];
  __shared__ float Linv[16];
  const int wave = threadIdx.x>>6, lane = threadIdx.x&63;
  const int xcd  = blockIdx.x & 7;
  const int slot = blockIdx.x >> 3;          // 0..779
  const int bh = xcd*12 + slot/65;
  const int qt = slot%65;
  const int b  = bh / 12, h = bh - b*12;
  const int qbase = qt*16;
  const int g = lane>>4, cl = lane&15;

  if (threadIdx.x < 16) Lrow[threadIdx.x] = 0.f;
  __syncthreads();

  const u16* qrow = Qp + ((size_t)bh*kNP + (qbase + cl))*kD + g*8;
  bf16x8 aq0 = *reinterpret_cast<const bf16x8*>(qrow);
  bf16x8 aq1 = *reinterpret_cast<const bf16x8*>(qrow + 32);

  // per-lane row mask*scale (one scalar: lane owns q-row = cl)
  const int qi_l = qbase + cl;
  const float mqc = (qi_l < kN && maskn[b*kN + qi_l] != 0) ? kScale : 0.f;

  // ---- phase 1: S^T = mfma(K,Q) -> e -> packed b64 LDS writes, row sums ----
  const u16* kb = Kp + (size_t)bh*kNP*kD;
  float rsum = 0.f;
  u16* erow = &E[cl*LDE];
  #pragma unroll 1
  for (int kt=wave; kt<32; kt+=8){
    const int ktb = kt*32;
    const u16* kr = kb + (size_t)(ktb+cl)*kD + g*8;
    bf16x8 b00 = *reinterpret_cast<const bf16x8*>(kr);
    bf16x8 b01 = *reinterpret_cast<const bf16x8*>(kr+32);
    bf16x8 b10 = *reinterpret_cast<const bf16x8*>(kr+1024);
    bf16x8 b11 = *reinterpret_cast<const bf16x8*>(kr+1024+32);
    f32x4 s0 = {0.f,0.f,0.f,0.f}, s1 = {0.f,0.f,0.f,0.f};
    __builtin_amdgcn_s_setprio(1);
    s0 = MFMA16(b00,aq0,s0); s0 = MFMA16(b01,aq1,s0);   // swapped: S^T rows=k
    s1 = MFMA16(b10,aq0,s1); s1 = MFMA16(b11,aq1,s1);
    __builtin_amdgcn_s_setprio(0);
    float e0 = __expf(s0[0]*mqc), e1 = __expf(s0[1]*mqc);
    float e2 = __expf(s0[2]*mqc), e3 = __expf(s0[3]*mqc);
    float f0 = __expf(s1[0]*mqc), f1 = __expf(s1[1]*mqc);
    float f2 = __expf(s1[2]*mqc), f3 = __expf(s1[3]*mqc);
    rsum += ((e0+e1)+(e2+e3)) + ((f0+f1)+(f2+f3));
    uint2 w0v = { pkbf(e0,e1), pkbf(e2,e3) };
    uint2 w1v = { pkbf(f0,f1), pkbf(f2,f3) };
    *reinterpret_cast<uint2*>(&erow[ktb + 4*g])      = w0v;
    *reinterpret_cast<uint2*>(&erow[ktb + 16 + 4*g]) = w1v;
  }
  if (wave == 0){
    // kt = 32 boundary tile: only col 1024 (g==0, elem 0) is valid
    const int ktb = 1024;
    const u16* kr = kb + (size_t)(ktb+cl)*kD + g*8;
    bf16x8 b00 = *reinterpret_cast<const bf16x8*>(kr);
    bf16x8 b01 = *reinterpret_cast<const bf16x8*>(kr+32);
    f32x4 s0 = {0.f,0.f,0.f,0.f};
    s0 = MFMA16(b00,aq0,s0); s0 = MFMA16(b01,aq1,s0);
    float e0 = (g==0) ? __expf(s0[0]*mqc) : 0.f;
    rsum += e0;
    uint2 w0v = { pkbf(e0,0.f), 0u };
    uint2 zz  = { 0u, 0u };
    *reinterpret_cast<uint2*>(&erow[ktb + 4*g])      = w0v;
    *reinterpret_cast<uint2*>(&erow[ktb + 16 + 4*g]) = zz;
  }
  // reduce across the 4 g-lanes holding each row, one atomic per row per wave
  rsum += __shfl_xor(rsum, 16);
  rsum += __shfl_xor(rsum, 32);
  if (lane < 16) atomicAdd(&Lrow[cl], rsum);
  __syncthreads();
  if (threadIdx.x < 16) Linv[threadIdx.x] = 1.f/Lrow[threadIdx.x];
  __syncthreads();

  if (wave < 4){
    // ---- phase 2b: PV; wave owns 16 d-cols (TLP-hidden, 1-deep) ----
    const int d0 = wave*16;
    f32x4 oacc = (f32x4){0.f,0.f,0.f,0.f};
    const u16* vb = Vt + ((size_t)bh*kD + d0 + cl)*kNP;
    for (int kt=0; kt<33; kt++){
      const int ko = kt*32 + g*8;
      bf16x8 pa = *reinterpret_cast<const bf16x8*>(&E[cl*LDE + ko]);
      bf16x8 vv = *reinterpret_cast<const bf16x8*>(vb + ko);
      oacc = MFMA16(pa, vv, oacc);
    }
    #pragma unroll
    for (int i=0;i<4;i++){
      int row = g*4+i, qi = qbase+row;
      if (qi < kN){
        float val = oacc[i] * Linv[row];
        int dd = d0 + cl;
        if (qi >= 1) val += b2f(Qp[((size_t)bh*kNP + qi)*kD + dd]);
        ctx[((size_t)(b*kN + qi))*kC + h*kD + dd] = f2b(val);
      }
    }
  } else {
    // ---- phase 2a: attn tile as ONE contiguous span (waves 4-7) ----
    const int t2 = threadIdx.x - 256;
    size_t S = (size_t)bh*kN*kN + (size_t)qbase*kN;
    float* tp = attn_out + S;
    int rows = kN - qbase; if (rows > 16) rows = 16;
    int T = rows*kN;
    int head = (int)((4 - (S & 3)) & 3);
    int body4 = (T - head) >> 2;
    int tail = T - head - body4*4;
    if (t2 < head){
      int e = t2;
      unsigned row = ((unsigned)(e*16369))>>24;
      int col = e - (int)row*kN;
      tp[e] = b2f(E[row*LDE+col]) * Linv[row];
    }
    if (t2 < tail){
      int e = head + body4*4 + t2;
      unsigned row = ((unsigned)(e*16369))>>24;
      int col = e - (int)row*kN;
      tp[e] = b2f(E[row*LDE+col]) * Linv[row];
    }
    for (int idx = t2; idx < body4; idx += 256){
      int e = head + idx*4;
      unsigned row0 = ((unsigned)(e*16369))>>24;
      unsigned row3 = ((unsigned)((e+3)*16369))>>24;
      float4 vv;
      if (row0 == row3){
        int col = e - (int)row0*kN;
        const u16* ep = &E[row0*LDE + col];
        float li = Linv[row0];
        vv.x = b2f(ep[0])*li; vv.y = b2f(ep[1])*li;
        vv.z = b2f(ep[2])*li; vv.w = b2f(ep[3])*li;
      } else {
        float tmp[4];
        #pragma unroll
        for (int j=0;j<4;j++){
          int ee = e+j;
          unsigned row = ((unsigned)(ee*16369))>>24;
          int col = ee - (int)row*kN;
          tmp[j] = b2f(E[row*LDE+col]) * Linv[row];
        }
        vv.x=tmp[0]; vv.y=tmp[1]; vv.z=tmp[2]; vv.w=tmp[3];
      }
      *reinterpret_cast<float4*>(tp + e) = vv;
    }
  }
}

extern "C" void kernel_launch(void* const* d_in, const int* in_sizes, int n_in,
                              void* d_out, int out_size, void* d_ws, size_t ws_size,
                              hipStream_t stream) {
  const float* x    = (const float*)d_in[0];
  const void*  msk  = d_in[1];
  const float* Wq   = (const float*)d_in[2];
  const float* Wk   = (const float*)d_in[3];
  const float* Wv   = (const float*)d_in[4];
  const float* pw_q = (const float*)d_in[5];
  const float* pw_k = (const float*)d_in[6];
  const float* pw_v = (const float*)d_in[7];
  const float* gq   = (const float*)d_in[8];
  const float* bq   = (const float*)d_in[9];
  const float* gk   = (const float*)d_in[10];
  const float* bk   = (const float*)d_in[11];
  const float* gv   = (const float*)d_in[12];
  const float* bv   = (const float*)d_in[13];
  const float* Wp   = (const float*)d_in[14];
  const float* bp   = (const float*)d_in[15];

  char* ws = (char*)d_ws;
  u16* xb     = (u16*)(ws + 0);            // 12,595,200 B
  u16* wb     = (u16*)(ws + 12595200);     // 4,718,592 B (Wq,Wk,Wv,Wp)
  int* maskn  = (int*)(ws + 17313792);
  u16* qkvmat = (u16*)(ws + 17346816);     // [8200][2304] bf16 = 37,785,600 B
  u16* Qp     = (u16*)(ws + 55132416);
  u16* Kp     = (u16*)(ws + 68108544);
  u16* Vt     = (u16*)(ws + 81084672);
  u16* ctx    = (u16*)(ws + 17346816);     // aliases qkvmat (free after pooling)

  float* out1 = (float*)d_out;
  float* attn = out1 + (size_t)kM*kC;

  k_prep<<<8486, 256, 0, stream>>>(reinterpret_cast<const float4*>(x),
                                   Wq, Wk, Wv, Wp, (const unsigned char*)msk,
                                   xb, wb, maskn);
  k_gemm128<0><<<65*18, 256, 0, stream>>>(xb, wb, nullptr, qkvmat, nullptr);
  k_pool3<<<dim3(96*17,3), 256, 0, stream>>>(qkvmat, pw_q, pw_k, pw_v,
                                             gq, bq, gk, bk, gv, bv, Qp, Kp, Vt);
  k_attn<<<96*65, 512, 0, stream>>>(Qp, Kp, Vt, maskn, attn, ctx);
  k_gemm128<1><<<65*6, 256, 0, stream>>>(ctx, wb, bp, nullptr, out1);
}